// Round 4
// baseline (473.348 us; speedup 1.0000x reference)
//
#include <hip/hip_runtime.h>
#include <hip/hip_bf16.h>
#include <stdint.h>

#define DEV __device__ __forceinline__

typedef float f32x4 __attribute__((ext_vector_type(4)));
typedef short s16x8 __attribute__((ext_vector_type(8)));
typedef __bf16 bf16x8 __attribute__((ext_vector_type(8)));
typedef unsigned short us8 __attribute__((ext_vector_type(8)));
typedef unsigned short u16;

// ---------- helpers ----------
DEV u16 f2bf(float f) {  // round-to-nearest-even f32 -> bf16
  uint32_t u = __builtin_bit_cast(uint32_t, f);
  u += 0x7FFFu + ((u >> 16) & 1u);
  return (u16)(u >> 16);
}
DEV float bf2f(u16 h) { return __builtin_bit_cast(float, (uint32_t)h << 16); }

DEV void gload16(const void* g, void* l) {
  __builtin_amdgcn_global_load_lds((__attribute__((address_space(1))) void*)(g),
                                   (__attribute__((address_space(3))) void*)(l),
                                   16, 0, 0);
}

DEV f32x4 mfma16(s16x8 a, s16x8 b, f32x4 c) {
  return __builtin_amdgcn_mfma_f32_16x16x32_bf16(
      __builtin_bit_cast(bf16x8, a), __builtin_bit_cast(bf16x8, b), c, 0, 0, 0);
}

// ---------- workspace layout (bytes) ----------
#define OFF_S0    0ul
#define OFF_S1    16384ul
#define OFF_SRGB  32768ul
#define OFF_D0    49152ul
#define OFF_D1    65536ul
#define OFF_WSQ0  81920ul
#define OFF_WSQ1  1130496ul
#define OFF_ZERO  2179072ul
#define OFF_X0M   2179328ul       // bf16 NHWC [8][32][32][512]
#define OFF_W0T   10567936ul      // bf16 [9 slice][512 o][512 c]
#define OFF_W1T   15286528ul      // bf16 [9 tap][512 o][512 c]
#define OFF_ZZ    20005120ul      // bf16 [4 phase][8 b][33*33 q][512 o]
#define OFF_X1M   55689472ul      // bf16 NHWC [8][64][64][512] (s1-modulated)
// end ~89.2 MB

// ---------- styles ----------
__global__ void styles_kernel(const float* __restrict__ wsv,
                              const float* __restrict__ a0w, const float* __restrict__ a0b,
                              const float* __restrict__ a1w, const float* __restrict__ a1b,
                              const float* __restrict__ argw, const float* __restrict__ argb,
                              float* __restrict__ s0, float* __restrict__ s1,
                              float* __restrict__ srgb) {
  const int idx = blockIdx.x * 4 + (threadIdx.x >> 6);
  const int lane = threadIdx.x & 63;
  const int l = idx >> 12, rem = idx & 4095, b = rem >> 9, o = rem & 511;
  const float* aw = (l == 0) ? a0w : ((l == 1) ? a1w : argw);
  const float* wrow = wsv + (b * 3 + l) * 512;
  const float* arow = aw + o * 512;
  float acc = 0.f;
#pragma unroll
  for (int k = 0; k < 8; ++k) acc += wrow[lane + 64 * k] * arow[lane + 64 * k];
#pragma unroll
  for (int off = 32; off; off >>= 1) acc += __shfl_xor(acc, off);
  if (lane == 0) {
    const float sg = 0.04419417382415922f;  // 1/sqrt(512)
    if (l == 0)      s0[b * 512 + o] = acc * sg + a0b[o];
    else if (l == 1) s1[b * 512 + o] = acc * sg + a1b[o];
    else             srgb[b * 512 + o] = (acc * sg + argb[o]) * sg;
  }
}

// ---------- w (512x512x3x3 f32) -> [slice][o][c] bf16 + wsq ----------
__global__ void prepWT_kernel(const float* __restrict__ w, u16* __restrict__ wt,
                              float* __restrict__ wsq) {
  const int idx = blockIdx.x * 256 + threadIdx.x;  // o*512+c
  float v[9], sq = 0.f;
#pragma unroll
  for (int t = 0; t < 9; ++t) { v[t] = w[idx * 9 + t]; sq += v[t] * v[t]; }
  wsq[idx] = sq;
#pragma unroll
  for (int t = 0; t < 9; ++t) wt[(size_t)t * 262144 + idx] = f2bf(v[t]);
}

// ---------- dcoef ----------
__global__ void dcoef_kernel(const float* __restrict__ s0, const float* __restrict__ s1,
                             const float* __restrict__ wsq0, const float* __restrict__ wsq1,
                             float* __restrict__ d0, float* __restrict__ d1) {
  const int idx = blockIdx.x * 4 + (threadIdx.x >> 6);
  const int lane = threadIdx.x & 63;
  const int layer = idx >> 12, rem = idx & 4095, b = rem >> 9, o = rem & 511;
  const float* s = layer ? s1 : s0;
  const float* wsq = layer ? wsq1 : wsq0;
  float acc = 0.f;
#pragma unroll
  for (int k = 0; k < 8; ++k) {
    const int c = lane + 64 * k;
    const float sv = s[b * 512 + c];
    acc += sv * sv * wsq[o * 512 + c];
  }
#pragma unroll
  for (int off = 32; off; off >>= 1) acc += __shfl_xor(acc, off);
  if (lane == 0) (layer ? d1 : d0)[b * 512 + o] = 1.f / sqrtf(acc + 1e-8f);
}

// ---------- x -> NHWC bf16 modulated by s0 ----------
__global__ void x0m_kernel(const float* __restrict__ x, const float* __restrict__ s0,
                           u16* __restrict__ out) {
  __shared__ u16 t[32 * 514];
  const int b = blockIdx.x >> 5, h = blockIdx.x & 31;
  const int tid = threadIdx.x;
  const int w = tid & 31, cs = tid >> 5;
  for (int c0 = 0; c0 < 512; c0 += 8) {
    const int c = c0 + cs;
    t[w * 514 + c] = f2bf(x[((b * 512 + c) * 32 + h) * 32 + w] * s0[b * 512 + c]);
  }
  __syncthreads();
  const int base = ((b * 32 + h) * 32) * 512;
  for (int i = 0; i < 64; ++i) {
    const int idx = i * 256 + tid;
    out[base + idx] = t[(idx >> 9) * 514 + (idx & 511)];
  }
}

// ---------- phase conv (transposed-conv phases of conv0, pre-FIR) ----------
// zz[2q+rho] decomposition: rho=0 axis taps {x[q-1]*w0[2], x[q]*w0[0]}, rho=1: {x[q]*w0[1]}.
// Per phase: sparse conv on the 33x33 q-grid (flat 1089 px, 5 tiles of 256).
// Staged B-tile: input rows r0-1..r0+8, cols -1..32 -> 10x34 units (1360, 6 chunks).
template <int PH>
DEV void phaseconv_body(char* smem, int tid, int lane, int wid, int l15, int l4,
                        int obase, int tile, int b,
                        const char* xin_c, const char* wt_c, u16* __restrict__ zz,
                        const char* __restrict__ zerobuf) {
  constexpr int NT = (PH == 0) ? 4 : ((PH == 3) ? 1 : 2);
  constexpr int SLt[4][4] = {{8, 6, 2, 0}, {7, 1, 0, 0}, {5, 3, 0, 0}, {4, 0, 0, 0}};
  constexpr int TYt[4][4] = {{0, 0, 1, 1}, {0, 1, 0, 0}, {1, 1, 0, 0}, {1, 0, 0, 0}};
  constexpr int TXt[4][4] = {{0, 1, 0, 1}, {1, 1, 0, 0}, {0, 1, 0, 0}, {1, 0, 0, 0}};
  constexpr int A_OFF = 24576;  // 6 B-chunks * 4096

  const int p0 = tile * 256;
  const int r0 = (p0 * 993) >> 15;   // floor(p0/33), exact for p0<1280
  const int row0 = r0 - 1;

  size_t boff[6];
  bool bval[6];
#pragma unroll
  for (int i = 0; i < 6; ++i) {
    const int u = i * 256 + tid;
    const int row = u / 136;
    const int rem = u - row * 136;
    const int k8 = rem / 34;
    const int col = rem - k8 * 34;
    const int ir = row0 + row;
    const int ic = col - 1;
    bval[i] = (u < 1360) && (ir >= 0) && (ir < 32) && (ic >= 0) && (ic < 32);
    boff[i] = ((size_t)((b * 32 + ir) * 32 + ic) * 512 + k8 * 8) * 2;
  }

  int ub[4], pp[4];
#pragma unroll
  for (int bc = 0; bc < 4; ++bc) {
    const int p = p0 + wid * 64 + bc * 16 + l15;
    pp[bc] = p;
    const int qy = (p * 993) >> 15;
    const int qx = p - qy * 33;
    ub[bc] = (((qy - r0) * 4 + l4) * 34 + qx) * 16;
  }

  const size_t aoffb = ((size_t)(obase + lane) * 512 + (size_t)wid * 8) * 2;

  f32x4 acc[4][4];
  const f32x4 fz = {0.f, 0.f, 0.f, 0.f};
#pragma unroll
  for (int i = 0; i < 4; ++i)
#pragma unroll
    for (int j = 0; j < 4; ++j) acc[i][j] = fz;

  for (int c0 = 0; c0 < 512; c0 += 32) {
#pragma unroll
    for (int i = 0; i < 6; ++i) {
      const void* src = bval[i] ? (const void*)(xin_c + boff[i] + (size_t)c0 * 2)
                                : (const void*)zerobuf;
      gload16(src, smem + i * 4096 + wid * 1024);
    }
#pragma unroll
    for (int t = 0; t < NT; ++t)
      gload16(wt_c + (size_t)SLt[PH][t] * 524288 + aoffb + (size_t)c0 * 2,
              smem + A_OFF + t * 4096 + wid * 1024);
    __syncthreads();
#pragma unroll
    for (int t = 0; t < NT; ++t) {
      s16x8 bfr[4], afr[4];
#pragma unroll
      for (int bc = 0; bc < 4; ++bc)
        bfr[bc] = *(const s16x8*)(smem + ub[bc] + (TYt[PH][t] * 136 + TXt[PH][t]) * 16);
#pragma unroll
      for (int f = 0; f < 4; ++f)
        afr[f] = *(const s16x8*)(smem + A_OFF + t * 4096 + (l4 * 64 + f * 16 + l15) * 16);
#pragma unroll
      for (int f = 0; f < 4; ++f)
#pragma unroll
        for (int bc = 0; bc < 4; ++bc)
          acc[f][bc] = mfma16(afr[f], bfr[bc], acc[f][bc]);
    }
    __syncthreads();
  }

  // epilogue: raw bf16 store of pre-FIR zz (no demod/noise here)
#pragma unroll
  for (int f = 0; f < 4; ++f) {
    const int o = obase + f * 16 + l4 * 4;
#pragma unroll
    for (int bc = 0; bc < 4; ++bc) {
      if (pp[bc] < 1089) {
        ushort4 pk;
        pk.x = f2bf(acc[f][bc][0]);
        pk.y = f2bf(acc[f][bc][1]);
        pk.z = f2bf(acc[f][bc][2]);
        pk.w = f2bf(acc[f][bc][3]);
        *(ushort4*)(zz + ((size_t)(PH * 8 + b) * 1089 + pp[bc]) * 512 + o) = pk;
      }
    }
  }
}

__global__ __launch_bounds__(256, 3) void phaseconv_kernel(
    const u16* __restrict__ xin, const u16* __restrict__ wt, u16* __restrict__ zz,
    const char* __restrict__ zerobuf) {
  __shared__ __align__(16) char smem[40960];
  const int tid = threadIdx.x;
  const int lane = tid & 63, wid = tid >> 6, l15 = lane & 15, l4 = lane >> 4;
  const int bid = blockIdx.x;       // [0,1280): ph-major so heavy blocks launch first
  const int ph = bid / 320;
  const int rr = bid - ph * 320;
  const int obIdx = rr & 7;
  const int r = rr >> 3;            // [0,40)
  const int tile = r % 5;
  const int b = r / 5;
  const int obase = obIdx * 64;
  const char* xin_c = (const char*)xin;
  const char* wt_c = (const char*)wt;
  switch (ph) {
    case 0: phaseconv_body<0>(smem, tid, lane, wid, l15, l4, obase, tile, b, xin_c, wt_c, zz, zerobuf); break;
    case 1: phaseconv_body<1>(smem, tid, lane, wid, l15, l4, obase, tile, b, xin_c, wt_c, zz, zerobuf); break;
    case 2: phaseconv_body<2>(smem, tid, lane, wid, l15, l4, obase, tile, b, xin_c, wt_c, zz, zerobuf); break;
    default: phaseconv_body<3>(smem, tid, lane, wid, l15, l4, obase, tile, b, xin_c, wt_c, zz, zerobuf); break;
  }
}

// ---------- FIR (4x4 upfirdn tail) + demod + noise + bias + lrelu + clamp + s1 ----------
// out[u,v] = sum_{ky,kx} kk[ky]kk[kx] * zz[(u-1+ky),(v-1+kx)] (phase-decomposed zz)
__global__ __launch_bounds__(256) void fir_kernel(
    const u16* __restrict__ zz, const float* __restrict__ dc0,
    const float* __restrict__ bias0, const float* __restrict__ noise0,
    const float* __restrict__ ns0, const float* __restrict__ s1,
    u16* __restrict__ x1m) {
  const int u = blockIdx.x & 63, b = blockIdx.x >> 6;
  const int tid = threadIdx.x;
  const int v = tid & 63, cg0 = tid >> 6;
  const float nz = noise0[u * 64 + v] * ns0[0];
  const float kk[4] = {0.25f, 0.75f, 0.75f, 0.25f};

  float wy[4], wx[4];
  int ry[4], qy[4], rx[4], qx[4];
#pragma unroll
  for (int k = 0; k < 4; ++k) {
    const int my = u - 1 + k;
    wy[k] = (my >= 0) ? kk[k] : 0.f;
    ry[k] = my & 1;
    qy[k] = (my >= 0) ? (my >> 1) : 0;
    const int mx = v - 1 + k;
    wx[k] = (mx >= 0) ? kk[k] : 0.f;
    rx[k] = mx & 1;
    qx[k] = (mx >= 0) ? (mx >> 1) : 0;
  }
  size_t off16[16];
  float w16[16];
#pragma unroll
  for (int ky = 0; ky < 4; ++ky)
#pragma unroll
    for (int kx = 0; kx < 4; ++kx) {
      const int phn = ry[ky] * 2 + rx[kx];
      off16[ky * 4 + kx] = ((size_t)(phn * 8 + b) * 1089 + qy[ky] * 33 + qx[kx]) * 512;
      w16[ky * 4 + kx] = wy[ky] * wx[kx];
    }

  for (int cgi = 0; cgi < 16; ++cgi) {
    const int c = cg0 * 8 + cgi * 32;
    float a[8] = {0.f, 0.f, 0.f, 0.f, 0.f, 0.f, 0.f, 0.f};
#pragma unroll
    for (int t = 0; t < 16; ++t) {
      const us8 zv = *(const us8*)(zz + off16[t] + c);
      const float w = w16[t];
#pragma unroll
      for (int r = 0; r < 8; ++r) a[r] = fmaf(w, bf2f(zv[r]), a[r]);
    }
    const float* dcp = dc0 + b * 512 + c;
    const float* bp = bias0 + c;
    const float* sp = s1 + b * 512 + c;
    us8 pk;
#pragma unroll
    for (int r = 0; r < 8; ++r) {
      float xv = a[r] * dcp[r] + nz + bp[r];
      xv = (xv < 0.f ? 0.2f * xv : xv) * 1.4142135623730951f;
      xv = fminf(fmaxf(xv, -256.f), 256.f);
      pk[r] = f2bf(xv * sp[r]);
    }
    *(us8*)(x1m + ((size_t)((b * 64 + u) * 64 + v) * 512 + c)) = pk;
  }
}

// ---------- conv1: implicit-GEMM MFMA 3x3 pad1 (round-1 verified structure) ----------
__global__ __launch_bounds__(256, 2) void conv1_kernel(
    const u16* __restrict__ xin, const u16* __restrict__ wt,
    const float* __restrict__ dcoef, const float* __restrict__ bias,
    const float* __restrict__ noise, const float* __restrict__ nstr,
    float* __restrict__ out_f32, const char* __restrict__ zerobuf) {
  __shared__ __align__(16) char smem[65536];
  const int tid = threadIdx.x;
  const int lane = tid & 63, wid = tid >> 6, l15 = lane & 15, l4 = lane >> 4;

  int bid = blockIdx.x;
  const int obIdx = bid & 7; bid >>= 3;
  const int tile = bid & 15;
  const int b = bid >> 4;
  const int obase = obIdx * 64;
  const int row0 = tile * 4 - 1;

  size_t boff[7];
  bool bval[7];
#pragma unroll
  for (int i = 0; i < 7; ++i) {
    const int u = i * 256 + tid;
    const int row = u / 264;
    const int rem = u - row * 264;
    const int k8 = rem / 66;
    const int col = rem - k8 * 66;
    const int ir = row0 + row;
    const int ic = col - 1;
    bval[i] = (row < 6) && (ir >= 0) && (ir < 64) && (ic >= 0) && (ic < 64);
    boff[i] = ((size_t)((b * 64 + ir) * 64 + ic) * 512 + k8 * 8) * 2;
  }

  int ub[4], jy[4], jx[4];
#pragma unroll
  for (int bc = 0; bc < 4; ++bc) {
    const int p = wid * 64 + bc * 16 + l15;
    const int pr = p >> 6, pc = p & 63;
    ub[bc] = ((pr * 4 + l4) * 66 + pc) * 16;
    jy[bc] = tile * 4 + pr;
    jx[bc] = pc;
  }

  const char* wt_c = (const char*)wt;
  const char* xin_c = (const char*)xin;
  const size_t aoffb = ((size_t)(obase + lane) * 512 + (size_t)wid * 8) * 2;

  f32x4 acc[4][4];
  const f32x4 fz = {0.f, 0.f, 0.f, 0.f};
#pragma unroll
  for (int i = 0; i < 4; ++i)
#pragma unroll
    for (int j = 0; j < 4; ++j) acc[i][j] = fz;

  for (int c0 = 0; c0 < 512; c0 += 32) {
#pragma unroll
    for (int i = 0; i < 7; ++i) {
      const void* src = bval[i] ? (const void*)(xin_c + boff[i] + (size_t)c0 * 2)
                                : (const void*)zerobuf;
      gload16(src, smem + i * 4096 + wid * 1024);
    }
#pragma unroll
    for (int t = 0; t < 9; ++t)
      gload16(wt_c + (size_t)t * 524288 + aoffb + (size_t)c0 * 2,
              smem + 28672 + t * 4096 + wid * 1024);
    __syncthreads();
#pragma unroll
    for (int t = 0; t < 9; ++t) {
      const int dyi = t / 3, dxi = t % 3;
      s16x8 bfr[4], afr[4];
#pragma unroll
      for (int bc = 0; bc < 4; ++bc)
        bfr[bc] = *(const s16x8*)(smem + ub[bc] + (dyi * 264 + dxi) * 16);
#pragma unroll
      for (int f = 0; f < 4; ++f)
        afr[f] = *(const s16x8*)(smem + 28672 + t * 4096 + (l4 * 64 + f * 16 + l15) * 16);
#pragma unroll
      for (int f = 0; f < 4; ++f)
#pragma unroll
        for (int bc = 0; bc < 4; ++bc)
          acc[f][bc] = mfma16(afr[f], bfr[bc], acc[f][bc]);
    }
    __syncthreads();
  }

  const float ns = nstr[0];
#pragma unroll
  for (int f = 0; f < 4; ++f) {
    const int o = obase + f * 16 + l4 * 4;
    const f32x4 dc = *(const f32x4*)(dcoef + b * 512 + o);
    const f32x4 bs = *(const f32x4*)(bias + o);
#pragma unroll
    for (int bc = 0; bc < 4; ++bc) {
      const float nz = noise[jy[bc] * 64 + jx[bc]] * ns;
#pragma unroll
      for (int r = 0; r < 4; ++r) {
        float xv = acc[f][bc][r] * dc[r] + nz + bs[r];
        xv = (xv < 0.f ? 0.2f * xv : xv) * 1.4142135623730951f;
        xv = fminf(fmaxf(xv, -256.f), 256.f);
        out_f32[((size_t)(b * 512 + o + r) * 64 + jy[bc]) * 64 + jx[bc]] = xv;
      }
    }
  }
}

// ---------- torgb (1x1 mod conv, f32) + img upsample + add ----------
__global__ void torgb_kernel(const float* __restrict__ xw, const float* __restrict__ img,
                             const float* __restrict__ srgb, const float* __restrict__ wrgb,
                             const float* __restrict__ brgb, float* __restrict__ imgout) {
  __shared__ float red[4][3][64];
  const int b = blockIdx.x >> 6, jy = blockIdx.x & 63;
  const int tid = threadIdx.x;
  const int jx = tid & 63, cg = tid >> 6;
  float p0 = 0.f, p1 = 0.f, p2 = 0.f;
  const float* xb = xw + ((size_t)(b * 512 + cg * 128) * 64 + jy) * 64 + jx;
  const float* sb = srgb + b * 512 + cg * 128;
  for (int i = 0; i < 128; ++i) {
    const float xs = xb[(size_t)i * 4096] * sb[i];
    const int c = cg * 128 + i;
    p0 += xs * wrgb[c];
    p1 += xs * wrgb[512 + c];
    p2 += xs * wrgb[1024 + c];
  }
  red[cg][0][jx] = p0; red[cg][1][jx] = p1; red[cg][2][jx] = p2;
  __syncthreads();
  if (cg == 0) {
    const int qy = jy >> 1, qx = jx >> 1;
    int ry[2]; float wy[2];
    if ((jy & 1) == 0) { ry[0] = qy - 1; wy[0] = 0.25f; ry[1] = qy; wy[1] = 0.75f; }
    else               { ry[0] = qy;     wy[0] = 0.75f; ry[1] = qy + 1; wy[1] = 0.25f; }
    int rx[2]; float wx[2];
    if ((jx & 1) == 0) { rx[0] = qx - 1; wx[0] = 0.25f; rx[1] = qx; wx[1] = 0.75f; }
    else               { rx[0] = qx;     wx[0] = 0.75f; rx[1] = qx + 1; wx[1] = 0.25f; }
#pragma unroll
    for (int o = 0; o < 3; ++o) {
      float y = red[0][o][jx] + red[1][o][jx] + red[2][o][jx] + red[3][o][jx] + brgb[o];
      y = fminf(fmaxf(y, -256.f), 256.f);
      float iv = 0.f;
#pragma unroll
      for (int a = 0; a < 2; ++a)
#pragma unroll
        for (int e = 0; e < 2; ++e)
          if (ry[a] >= 0 && ry[a] < 32 && rx[e] >= 0 && rx[e] < 32)
            iv += wy[a] * wx[e] * img[((b * 3 + o) * 32 + ry[a]) * 32 + rx[e]];
      imgout[((b * 3 + o) * 64 + jy) * 64 + jx] = y + iv;
    }
  }
}

// ---------- launch ----------
extern "C" void kernel_launch(void* const* d_in, const int* in_sizes, int n_in,
                              void* d_out, int out_size, void* d_ws, size_t ws_size,
                              hipStream_t stream) {
  (void)in_sizes; (void)n_in; (void)out_size; (void)ws_size;
  const float* x    = (const float*)d_in[0];
  const float* img  = (const float*)d_in[1];
  const float* wsv  = (const float*)d_in[2];
  const float* a0w  = (const float*)d_in[3];
  const float* a0b  = (const float*)d_in[4];
  const float* w0   = (const float*)d_in[5];
  const float* b0   = (const float*)d_in[6];
  const float* ns0  = (const float*)d_in[7];
  const float* nc0  = (const float*)d_in[8];
  const float* a1w  = (const float*)d_in[9];
  const float* a1b  = (const float*)d_in[10];
  const float* w1   = (const float*)d_in[11];
  const float* b1   = (const float*)d_in[12];
  const float* ns1  = (const float*)d_in[13];
  const float* nc1  = (const float*)d_in[14];
  const float* argw = (const float*)d_in[15];
  const float* argb = (const float*)d_in[16];
  const float* wrgb = (const float*)d_in[17];
  const float* brgb = (const float*)d_in[18];

  char* wsb = (char*)d_ws;
  float* s0   = (float*)(wsb + OFF_S0);
  float* s1   = (float*)(wsb + OFF_S1);
  float* srgb = (float*)(wsb + OFF_SRGB);
  float* dd0  = (float*)(wsb + OFF_D0);
  float* dd1  = (float*)(wsb + OFF_D1);
  float* wsq0 = (float*)(wsb + OFF_WSQ0);
  float* wsq1 = (float*)(wsb + OFF_WSQ1);
  char*  zero = wsb + OFF_ZERO;
  u16*   x0m  = (u16*)(wsb + OFF_X0M);
  u16*   w0t  = (u16*)(wsb + OFF_W0T);
  u16*   w1t  = (u16*)(wsb + OFF_W1T);
  u16*   zz   = (u16*)(wsb + OFF_ZZ);
  u16*   x1m  = (u16*)(wsb + OFF_X1M);

  float* out_x   = (float*)d_out;
  float* out_img = out_x + 16777216;

  hipMemsetAsync(zero, 0, 256, stream);
  styles_kernel<<<3072, 256, 0, stream>>>(wsv, a0w, a0b, a1w, a1b, argw, argb, s0, s1, srgb);
  prepWT_kernel<<<1024, 256, 0, stream>>>(w0, w0t, wsq0);
  prepWT_kernel<<<1024, 256, 0, stream>>>(w1, w1t, wsq1);
  dcoef_kernel<<<2048, 256, 0, stream>>>(s0, s1, wsq0, wsq1, dd0, dd1);
  x0m_kernel<<<256, 256, 0, stream>>>(x, s0, x0m);
  phaseconv_kernel<<<1280, 256, 0, stream>>>(x0m, w0t, zz, zero);
  fir_kernel<<<512, 256, 0, stream>>>(zz, dd0, b0, nc0, ns0, s1, x1m);
  conv1_kernel<<<1024, 256, 0, stream>>>(x1m, w1t, dd1, b1, nc1, ns1, out_x, zero);
  torgb_kernel<<<512, 256, 0, stream>>>(out_x, img, srgb, wrgb, brgb, out_img);
}

// Round 6
// 459.444 us; speedup vs baseline: 1.0303x; 1.0303x over previous
//
#include <hip/hip_runtime.h>
#include <hip/hip_bf16.h>
#include <stdint.h>

#define DEV __device__ __forceinline__

typedef float f32x4 __attribute__((ext_vector_type(4)));
typedef short s16x8 __attribute__((ext_vector_type(8)));
typedef __bf16 bf16x8 __attribute__((ext_vector_type(8)));
typedef unsigned short us8 __attribute__((ext_vector_type(8)));
typedef unsigned short u16;

// ---------- helpers ----------
DEV u16 f2bf(float f) {  // round-to-nearest-even f32 -> bf16
  uint32_t u = __builtin_bit_cast(uint32_t, f);
  u += 0x7FFFu + ((u >> 16) & 1u);
  return (u16)(u >> 16);
}
DEV float bf2f(u16 h) { return __builtin_bit_cast(float, (uint32_t)h << 16); }

DEV void gload16(const void* g, void* l) {
  __builtin_amdgcn_global_load_lds((__attribute__((address_space(1))) void*)(g),
                                   (__attribute__((address_space(3))) void*)(l),
                                   16, 0, 0);
}

DEV f32x4 mfma16(s16x8 a, s16x8 b, f32x4 c) {
  return __builtin_amdgcn_mfma_f32_16x16x32_bf16(
      __builtin_bit_cast(bf16x8, a), __builtin_bit_cast(bf16x8, b), c, 0, 0, 0);
}

// ---------- workspace layout (bytes) ----------
#define OFF_S0    0ul
#define OFF_S1    16384ul
#define OFF_SRGB  32768ul
#define OFF_D0    49152ul
#define OFF_D1    65536ul
#define OFF_WSQ0  81920ul
#define OFF_WSQ1  1130496ul
#define OFF_ZERO  2179072ul
#define OFF_X0M   2179328ul       // bf16 NHWC [8][32][32][512]
#define OFF_W0T   10567936ul      // bf16 [9 slice][512 o][512 c]
#define OFF_W1T   15286528ul      // bf16 [9 tap][512 o][512 c]
#define OFF_ZZ    20005120ul      // bf16 [4 phase][8 b][33*33 q][512 o]
#define OFF_X1M   55689472ul      // bf16 NHWC [8][64][64][512] (s1-modulated)
// end ~89.2 MB

// ---------- styles ----------
__global__ void styles_kernel(const float* __restrict__ wsv,
                              const float* __restrict__ a0w, const float* __restrict__ a0b,
                              const float* __restrict__ a1w, const float* __restrict__ a1b,
                              const float* __restrict__ argw, const float* __restrict__ argb,
                              float* __restrict__ s0, float* __restrict__ s1,
                              float* __restrict__ srgb) {
  const int idx = blockIdx.x * 4 + (threadIdx.x >> 6);
  const int lane = threadIdx.x & 63;
  const int l = idx >> 12, rem = idx & 4095, b = rem >> 9, o = rem & 511;
  const float* aw = (l == 0) ? a0w : ((l == 1) ? a1w : argw);
  const float* wrow = wsv + (b * 3 + l) * 512;
  const float* arow = aw + o * 512;
  float acc = 0.f;
#pragma unroll
  for (int k = 0; k < 8; ++k) acc += wrow[lane + 64 * k] * arow[lane + 64 * k];
#pragma unroll
  for (int off = 32; off; off >>= 1) acc += __shfl_xor(acc, off);
  if (lane == 0) {
    const float sg = 0.04419417382415922f;  // 1/sqrt(512)
    if (l == 0)      s0[b * 512 + o] = acc * sg + a0b[o];
    else if (l == 1) s1[b * 512 + o] = acc * sg + a1b[o];
    else             srgb[b * 512 + o] = (acc * sg + argb[o]) * sg;
  }
}

// ---------- w (512x512x3x3 f32) -> [slice][o][c] bf16 + wsq ----------
__global__ void prepWT_kernel(const float* __restrict__ w, u16* __restrict__ wt,
                              float* __restrict__ wsq) {
  const int idx = blockIdx.x * 256 + threadIdx.x;  // o*512+c
  float v[9], sq = 0.f;
#pragma unroll
  for (int t = 0; t < 9; ++t) { v[t] = w[idx * 9 + t]; sq += v[t] * v[t]; }
  wsq[idx] = sq;
#pragma unroll
  for (int t = 0; t < 9; ++t) wt[(size_t)t * 262144 + idx] = f2bf(v[t]);
}

// ---------- dcoef ----------
__global__ void dcoef_kernel(const float* __restrict__ s0, const float* __restrict__ s1,
                             const float* __restrict__ wsq0, const float* __restrict__ wsq1,
                             float* __restrict__ d0, float* __restrict__ d1) {
  const int idx = blockIdx.x * 4 + (threadIdx.x >> 6);
  const int lane = threadIdx.x & 63;
  const int layer = idx >> 12, rem = idx & 4095, b = rem >> 9, o = rem & 511;
  const float* s = layer ? s1 : s0;
  const float* wsq = layer ? wsq1 : wsq0;
  float acc = 0.f;
#pragma unroll
  for (int k = 0; k < 8; ++k) {
    const int c = lane + 64 * k;
    const float sv = s[b * 512 + c];
    acc += sv * sv * wsq[o * 512 + c];
  }
#pragma unroll
  for (int off = 32; off; off >>= 1) acc += __shfl_xor(acc, off);
  if (lane == 0) (layer ? d1 : d0)[b * 512 + o] = 1.f / sqrtf(acc + 1e-8f);
}

// ---------- x -> NHWC bf16 modulated by s0 ----------
__global__ void x0m_kernel(const float* __restrict__ x, const float* __restrict__ s0,
                           u16* __restrict__ out) {
  __shared__ u16 t[32 * 514];
  const int b = blockIdx.x >> 5, h = blockIdx.x & 31;
  const int tid = threadIdx.x;
  const int w = tid & 31, cs = tid >> 5;
  for (int c0 = 0; c0 < 512; c0 += 8) {
    const int c = c0 + cs;
    t[w * 514 + c] = f2bf(x[((b * 512 + c) * 32 + h) * 32 + w] * s0[b * 512 + c]);
  }
  __syncthreads();
  const int base = ((b * 32 + h) * 32) * 512;
  for (int i = 0; i < 64; ++i) {
    const int idx = i * 256 + tid;
    out[base + idx] = t[(idx >> 9) * 514 + (idx & 511)];
  }
}

// ---------- phase conv (transposed-conv phases of conv0, pre-FIR) ----------
template <int PH>
DEV void phaseconv_body(char* smem, int tid, int lane, int wid, int l15, int l4,
                        int obase, int tile, int b,
                        const char* xin_c, const char* wt_c, u16* __restrict__ zz,
                        const char* __restrict__ zerobuf) {
  constexpr int NT = (PH == 0) ? 4 : ((PH == 3) ? 1 : 2);
  constexpr int SLt[4][4] = {{8, 6, 2, 0}, {7, 1, 0, 0}, {5, 3, 0, 0}, {4, 0, 0, 0}};
  constexpr int TYt[4][4] = {{0, 0, 1, 1}, {0, 1, 0, 0}, {1, 1, 0, 0}, {1, 0, 0, 0}};
  constexpr int TXt[4][4] = {{0, 1, 0, 1}, {1, 1, 0, 0}, {0, 1, 0, 0}, {1, 0, 0, 0}};
  constexpr int A_OFF = 24576;  // 6 B-chunks * 4096

  const int p0 = tile * 256;
  const int r0 = (p0 * 993) >> 15;   // floor(p0/33), exact for p0<1280
  const int row0 = r0 - 1;

  size_t boff[6];
  bool bval[6];
#pragma unroll
  for (int i = 0; i < 6; ++i) {
    const int u = i * 256 + tid;
    const int row = u / 136;
    const int rem = u - row * 136;
    const int k8 = rem / 34;
    const int col = rem - k8 * 34;
    const int ir = row0 + row;
    const int ic = col - 1;
    bval[i] = (u < 1360) && (ir >= 0) && (ir < 32) && (ic >= 0) && (ic < 32);
    boff[i] = ((size_t)((b * 32 + ir) * 32 + ic) * 512 + k8 * 8) * 2;
  }

  int ub[4], pp[4];
#pragma unroll
  for (int bc = 0; bc < 4; ++bc) {
    const int p = p0 + wid * 64 + bc * 16 + l15;
    pp[bc] = p;
    const int qy = (p * 993) >> 15;
    const int qx = p - qy * 33;
    ub[bc] = (((qy - r0) * 4 + l4) * 34 + qx) * 16;
  }

  const size_t aoffb = ((size_t)(obase + lane) * 512 + (size_t)wid * 8) * 2;

  f32x4 acc[4][4];
  const f32x4 fz = {0.f, 0.f, 0.f, 0.f};
#pragma unroll
  for (int i = 0; i < 4; ++i)
#pragma unroll
    for (int j = 0; j < 4; ++j) acc[i][j] = fz;

  for (int c0 = 0; c0 < 512; c0 += 32) {
#pragma unroll
    for (int i = 0; i < 6; ++i) {
      const void* src = bval[i] ? (const void*)(xin_c + boff[i] + (size_t)c0 * 2)
                                : (const void*)zerobuf;
      gload16(src, smem + i * 4096 + wid * 1024);
    }
#pragma unroll
    for (int t = 0; t < NT; ++t)
      gload16(wt_c + (size_t)SLt[PH][t] * 524288 + aoffb + (size_t)c0 * 2,
              smem + A_OFF + t * 4096 + wid * 1024);
    __syncthreads();
#pragma unroll
    for (int t = 0; t < NT; ++t) {
      s16x8 bfr[4], afr[4];
#pragma unroll
      for (int bc = 0; bc < 4; ++bc)
        bfr[bc] = *(const s16x8*)(smem + ub[bc] + (TYt[PH][t] * 136 + TXt[PH][t]) * 16);
#pragma unroll
      for (int f = 0; f < 4; ++f)
        afr[f] = *(const s16x8*)(smem + A_OFF + t * 4096 + (l4 * 64 + f * 16 + l15) * 16);
#pragma unroll
      for (int f = 0; f < 4; ++f)
#pragma unroll
        for (int bc = 0; bc < 4; ++bc)
          acc[f][bc] = mfma16(afr[f], bfr[bc], acc[f][bc]);
    }
    __syncthreads();
  }

  // epilogue: raw bf16 store of pre-FIR zz
#pragma unroll
  for (int f = 0; f < 4; ++f) {
    const int o = obase + f * 16 + l4 * 4;
#pragma unroll
    for (int bc = 0; bc < 4; ++bc) {
      if (pp[bc] < 1089) {
        ushort4 pk;
        pk.x = f2bf(acc[f][bc][0]);
        pk.y = f2bf(acc[f][bc][1]);
        pk.z = f2bf(acc[f][bc][2]);
        pk.w = f2bf(acc[f][bc][3]);
        *(ushort4*)(zz + ((size_t)(PH * 8 + b) * 1089 + pp[bc]) * 512 + o) = pk;
      }
    }
  }
}

__global__ __launch_bounds__(256, 3) void phaseconv_kernel(
    const u16* __restrict__ xin, const u16* __restrict__ wt, u16* __restrict__ zz,
    const char* __restrict__ zerobuf) {
  __shared__ __align__(16) char smem[40960];
  const int tid = threadIdx.x;
  const int lane = tid & 63, wid = tid >> 6, l15 = lane & 15, l4 = lane >> 4;
  const int bid = blockIdx.x;       // ph-major so heavy blocks launch first
  const int ph = bid / 320;
  const int rr = bid - ph * 320;
  const int obIdx = rr & 7;
  const int r = rr >> 3;
  const int tile = r % 5;
  const int b = r / 5;
  const int obase = obIdx * 64;
  const char* xin_c = (const char*)xin;
  const char* wt_c = (const char*)wt;
  switch (ph) {
    case 0: phaseconv_body<0>(smem, tid, lane, wid, l15, l4, obase, tile, b, xin_c, wt_c, zz, zerobuf); break;
    case 1: phaseconv_body<1>(smem, tid, lane, wid, l15, l4, obase, tile, b, xin_c, wt_c, zz, zerobuf); break;
    case 2: phaseconv_body<2>(smem, tid, lane, wid, l15, l4, obase, tile, b, xin_c, wt_c, zz, zerobuf); break;
    default: phaseconv_body<3>(smem, tid, lane, wid, l15, l4, obase, tile, b, xin_c, wt_c, zz, zerobuf); break;
  }
}

// ---------- FIR (4x4 upfirdn tail) + demod + noise + bias + lrelu + clamp + s1 ----------
// COALESCED: lane -> channel (64 lanes x us8 = 512 contiguous ch), tid>>6 -> v-group.
__global__ __launch_bounds__(256) void fir_kernel(
    const u16* __restrict__ zz, const float* __restrict__ dc0,
    const float* __restrict__ bias0, const float* __restrict__ noise0,
    const float* __restrict__ ns0, const float* __restrict__ s1,
    u16* __restrict__ x1m) {
  const int u = blockIdx.x & 63, b = blockIdx.x >> 6;
  const int tid = threadIdx.x;
  const int lane = tid & 63, vg = tid >> 6;
  const int c = lane * 8;
  const float kk[4] = {0.25f, 0.75f, 0.75f, 0.25f};

  float wy[4]; int ry[4], qy[4];
#pragma unroll
  for (int k = 0; k < 4; ++k) {
    const int my = u - 1 + k;
    wy[k] = (my >= 0) ? kk[k] : 0.f;
    ry[k] = my & 1;
    qy[k] = (my >= 0) ? (my >> 1) : 0;
  }
  // per-thread channel params (hoisted, scalar loads)
  float dcv[8], bv[8], sv[8];
#pragma unroll
  for (int r = 0; r < 8; ++r) {
    dcv[r] = dc0[b * 512 + c + r];
    bv[r]  = bias0[c + r];
    sv[r]  = s1[b * 512 + c + r];
  }
  const float nsc = ns0[0];

  for (int vi = 0; vi < 16; ++vi) {
    const int v = vg * 16 + vi;
    float wx[4]; int rx[4], qx[4];
#pragma unroll
    for (int k = 0; k < 4; ++k) {
      const int mx = v - 1 + k;
      wx[k] = (mx >= 0) ? kk[k] : 0.f;
      rx[k] = mx & 1;
      qx[k] = (mx >= 0) ? (mx >> 1) : 0;
    }
    float a[8] = {0.f, 0.f, 0.f, 0.f, 0.f, 0.f, 0.f, 0.f};
#pragma unroll
    for (int ky = 0; ky < 4; ++ky)
#pragma unroll
      for (int kx = 0; kx < 4; ++kx) {
        const size_t off = ((size_t)((ry[ky] * 2 + rx[kx]) * 8 + b) * 1089 +
                            qy[ky] * 33 + qx[kx]) * 512 + c;
        const us8 zv = *(const us8*)(zz + off);
        const float w = wy[ky] * wx[kx];
#pragma unroll
        for (int r = 0; r < 8; ++r) a[r] = fmaf(w, bf2f(zv[r]), a[r]);
      }
    const float nz = noise0[u * 64 + v] * nsc;
    us8 pk;
#pragma unroll
    for (int r = 0; r < 8; ++r) {
      float xv = a[r] * dcv[r] + nz + bv[r];
      xv = (xv < 0.f ? 0.2f * xv : xv) * 1.4142135623730951f;
      xv = fminf(fmaxf(xv, -256.f), 256.f);
      pk[r] = f2bf(xv * sv[r]);
    }
    *(us8*)(x1m + ((size_t)((b * 64 + u) * 64 + v) * 512 + c)) = pk;
  }
}

// ---------- conv1: implicit-GEMM MFMA 3x3 pad1 (round-1 verified structure) ----------
__global__ __launch_bounds__(256, 2) void conv1_kernel(
    const u16* __restrict__ xin, const u16* __restrict__ wt,
    const float* __restrict__ dcoef, const float* __restrict__ bias,
    const float* __restrict__ noise, const float* __restrict__ nstr,
    float* __restrict__ out_f32, const char* __restrict__ zerobuf) {
  __shared__ __align__(16) char smem[65536];
  const int tid = threadIdx.x;
  const int lane = tid & 63, wid = tid >> 6, l15 = lane & 15, l4 = lane >> 4;

  int bid = blockIdx.x;
  const int obIdx = bid & 7; bid >>= 3;
  const int tile = bid & 15;
  const int b = bid >> 4;
  const int obase = obIdx * 64;
  const int row0 = tile * 4 - 1;

  size_t boff[7];
  bool bval[7];
#pragma unroll
  for (int i = 0; i < 7; ++i) {
    const int u = i * 256 + tid;
    const int row = u / 264;
    const int rem = u - row * 264;
    const int k8 = rem / 66;
    const int col = rem - k8 * 66;
    const int ir = row0 + row;
    const int ic = col - 1;
    bval[i] = (row < 6) && (ir >= 0) && (ir < 64) && (ic >= 0) && (ic < 64);
    boff[i] = ((size_t)((b * 64 + ir) * 64 + ic) * 512 + k8 * 8) * 2;
  }

  int ub[4], jy[4], jx[4];
#pragma unroll
  for (int bc = 0; bc < 4; ++bc) {
    const int p = wid * 64 + bc * 16 + l15;
    const int pr = p >> 6, pc = p & 63;
    ub[bc] = ((pr * 4 + l4) * 66 + pc) * 16;
    jy[bc] = tile * 4 + pr;
    jx[bc] = pc;
  }

  const char* wt_c = (const char*)wt;
  const char* xin_c = (const char*)xin;
  const size_t aoffb = ((size_t)(obase + lane) * 512 + (size_t)wid * 8) * 2;

  f32x4 acc[4][4];
  const f32x4 fz = {0.f, 0.f, 0.f, 0.f};
#pragma unroll
  for (int i = 0; i < 4; ++i)
#pragma unroll
    for (int j = 0; j < 4; ++j) acc[i][j] = fz;

  for (int c0 = 0; c0 < 512; c0 += 32) {
#pragma unroll
    for (int i = 0; i < 7; ++i) {
      const void* src = bval[i] ? (const void*)(xin_c + boff[i] + (size_t)c0 * 2)
                                : (const void*)zerobuf;
      gload16(src, smem + i * 4096 + wid * 1024);
    }
#pragma unroll
    for (int t = 0; t < 9; ++t)
      gload16(wt_c + (size_t)t * 524288 + aoffb + (size_t)c0 * 2,
              smem + 28672 + t * 4096 + wid * 1024);
    __syncthreads();
#pragma unroll
    for (int t = 0; t < 9; ++t) {
      const int dyi = t / 3, dxi = t % 3;
      s16x8 bfr[4], afr[4];
#pragma unroll
      for (int bc = 0; bc < 4; ++bc)
        bfr[bc] = *(const s16x8*)(smem + ub[bc] + (dyi * 264 + dxi) * 16);
#pragma unroll
      for (int f = 0; f < 4; ++f)
        afr[f] = *(const s16x8*)(smem + 28672 + t * 4096 + (l4 * 64 + f * 16 + l15) * 16);
#pragma unroll
      for (int f = 0; f < 4; ++f)
#pragma unroll
        for (int bc = 0; bc < 4; ++bc)
          acc[f][bc] = mfma16(afr[f], bfr[bc], acc[f][bc]);
    }
    __syncthreads();
  }

  const float ns = nstr[0];
#pragma unroll
  for (int f = 0; f < 4; ++f) {
    const int o = obase + f * 16 + l4 * 4;
    const f32x4 dc = *(const f32x4*)(dcoef + b * 512 + o);
    const f32x4 bs = *(const f32x4*)(bias + o);
#pragma unroll
    for (int bc = 0; bc < 4; ++bc) {
      const float nz = noise[jy[bc] * 64 + jx[bc]] * ns;
#pragma unroll
      for (int r = 0; r < 4; ++r) {
        float xv = acc[f][bc][r] * dc[r] + nz + bs[r];
        xv = (xv < 0.f ? 0.2f * xv : xv) * 1.4142135623730951f;
        xv = fminf(fmaxf(xv, -256.f), 256.f);
        out_f32[((size_t)(b * 512 + o + r) * 64 + jy[bc]) * 64 + jx[bc]] = xv;
      }
    }
  }
}

// ---------- torgb (1x1 mod conv, f32) + img upsample + add ----------
__global__ void torgb_kernel(const float* __restrict__ xw, const float* __restrict__ img,
                             const float* __restrict__ srgb, const float* __restrict__ wrgb,
                             const float* __restrict__ brgb, float* __restrict__ imgout) {
  __shared__ float red[4][3][64];
  const int b = blockIdx.x >> 6, jy = blockIdx.x & 63;
  const int tid = threadIdx.x;
  const int jx = tid & 63, cg = tid >> 6;
  float p0 = 0.f, p1 = 0.f, p2 = 0.f;
  const float* xb = xw + ((size_t)(b * 512 + cg * 128) * 64 + jy) * 64 + jx;
  const float* sb = srgb + b * 512 + cg * 128;
  for (int i = 0; i < 128; ++i) {
    const float xs = xb[(size_t)i * 4096] * sb[i];
    const int c = cg * 128 + i;
    p0 += xs * wrgb[c];
    p1 += xs * wrgb[512 + c];
    p2 += xs * wrgb[1024 + c];
  }
  red[cg][0][jx] = p0; red[cg][1][jx] = p1; red[cg][2][jx] = p2;
  __syncthreads();
  if (cg == 0) {
    const int qy = jy >> 1, qx = jx >> 1;
    int ry[2]; float wy[2];
    if ((jy & 1) == 0) { ry[0] = qy - 1; wy[0] = 0.25f; ry[1] = qy; wy[1] = 0.75f; }
    else               { ry[0] = qy;     wy[0] = 0.75f; ry[1] = qy + 1; wy[1] = 0.25f; }
    int rx[2]; float wx[2];
    if ((jx & 1) == 0) { rx[0] = qx - 1; wx[0] = 0.25f; rx[1] = qx; wx[1] = 0.75f; }
    else               { rx[0] = qx;     wx[0] = 0.75f; rx[1] = qx + 1; wx[1] = 0.25f; }
#pragma unroll
    for (int o = 0; o < 3; ++o) {
      float y = red[0][o][jx] + red[1][o][jx] + red[2][o][jx] + red[3][o][jx] + brgb[o];
      y = fminf(fmaxf(y, -256.f), 256.f);
      float iv = 0.f;
#pragma unroll
      for (int a = 0; a < 2; ++a)
#pragma unroll
        for (int e = 0; e < 2; ++e)
          if (ry[a] >= 0 && ry[a] < 32 && rx[e] >= 0 && rx[e] < 32)
            iv += wy[a] * wx[e] * img[((b * 3 + o) * 32 + ry[a]) * 32 + rx[e]];
      imgout[((b * 3 + o) * 64 + jy) * 64 + jx] = y + iv;
    }
  }
}

// ---------- launch ----------
extern "C" void kernel_launch(void* const* d_in, const int* in_sizes, int n_in,
                              void* d_out, int out_size, void* d_ws, size_t ws_size,
                              hipStream_t stream) {
  (void)in_sizes; (void)n_in; (void)out_size; (void)ws_size;
  const float* x    = (const float*)d_in[0];
  const float* img  = (const float*)d_in[1];
  const float* wsv  = (const float*)d_in[2];
  const float* a0w  = (const float*)d_in[3];
  const float* a0b  = (const float*)d_in[4];
  const float* w0   = (const float*)d_in[5];
  const float* b0   = (const float*)d_in[6];
  const float* ns0  = (const float*)d_in[7];
  const float* nc0  = (const float*)d_in[8];
  const float* a1w  = (const float*)d_in[9];
  const float* a1b  = (const float*)d_in[10];
  const float* w1   = (const float*)d_in[11];
  const float* b1   = (const float*)d_in[12];
  const float* ns1  = (const float*)d_in[13];
  const float* nc1  = (const float*)d_in[14];
  const float* argw = (const float*)d_in[15];
  const float* argb = (const float*)d_in[16];
  const float* wrgb = (const float*)d_in[17];
  const float* brgb = (const float*)d_in[18];

  char* wsb = (char*)d_ws;
  float* s0   = (float*)(wsb + OFF_S0);
  float* s1   = (float*)(wsb + OFF_S1);
  float* srgb = (float*)(wsb + OFF_SRGB);
  float* dd0  = (float*)(wsb + OFF_D0);
  float* dd1  = (float*)(wsb + OFF_D1);
  float* wsq0 = (float*)(wsb + OFF_WSQ0);
  float* wsq1 = (float*)(wsb + OFF_WSQ1);
  char*  zero = wsb + OFF_ZERO;
  u16*   x0m  = (u16*)(wsb + OFF_X0M);
  u16*   w0t  = (u16*)(wsb + OFF_W0T);
  u16*   w1t  = (u16*)(wsb + OFF_W1T);
  u16*   zz   = (u16*)(wsb + OFF_ZZ);
  u16*   x1m  = (u16*)(wsb + OFF_X1M);

  float* out_x   = (float*)d_out;
  float* out_img = out_x + 16777216;

  hipMemsetAsync(zero, 0, 256, stream);
  styles_kernel<<<3072, 256, 0, stream>>>(wsv, a0w, a0b, a1w, a1b, argw, argb, s0, s1, srgb);
  prepWT_kernel<<<1024, 256, 0, stream>>>(w0, w0t, wsq0);
  prepWT_kernel<<<1024, 256, 0, stream>>>(w1, w1t, wsq1);
  dcoef_kernel<<<2048, 256, 0, stream>>>(s0, s1, wsq0, wsq1, dd0, dd1);
  x0m_kernel<<<256, 256, 0, stream>>>(x, s0, x0m);
  phaseconv_kernel<<<1280, 256, 0, stream>>>(x0m, w0t, zz, zero);
  fir_kernel<<<512, 256, 0, stream>>>(zz, dd0, b0, nc0, ns0, s1, x1m);
  conv1_kernel<<<1024, 256, 0, stream>>>(x1m, w1t, dd1, b1, nc1, ns1, out_x, zero);
  torgb_kernel<<<512, 256, 0, stream>>>(out_x, img, srgb, wrgb, brgb, out_img);
}

// Round 7
// 448.032 us; speedup vs baseline: 1.0565x; 1.0255x over previous
//
#include <hip/hip_runtime.h>
#include <hip/hip_bf16.h>
#include <stdint.h>

#define DEV __device__ __forceinline__

typedef float f32x4 __attribute__((ext_vector_type(4)));
typedef short s16x8 __attribute__((ext_vector_type(8)));
typedef __bf16 bf16x8 __attribute__((ext_vector_type(8)));
typedef unsigned short us8 __attribute__((ext_vector_type(8)));
typedef unsigned short u16;

// ---------- helpers ----------
DEV u16 f2bf(float f) {  // round-to-nearest-even f32 -> bf16
  uint32_t u = __builtin_bit_cast(uint32_t, f);
  u += 0x7FFFu + ((u >> 16) & 1u);
  return (u16)(u >> 16);
}
DEV float bf2f(u16 h) { return __builtin_bit_cast(float, (uint32_t)h << 16); }

DEV void gload16(const void* g, void* l) {
  __builtin_amdgcn_global_load_lds((__attribute__((address_space(1))) void*)(g),
                                   (__attribute__((address_space(3))) void*)(l),
                                   16, 0, 0);
}

DEV f32x4 mfma16(s16x8 a, s16x8 b, f32x4 c) {
  return __builtin_amdgcn_mfma_f32_16x16x32_bf16(
      __builtin_bit_cast(bf16x8, a), __builtin_bit_cast(bf16x8, b), c, 0, 0, 0);
}

// ---------- workspace layout (bytes) ----------
#define OFF_S0    0ul
#define OFF_S1    16384ul
#define OFF_SRGB  32768ul
#define OFF_D0    49152ul
#define OFF_D1    65536ul
#define OFF_WSQ0  81920ul
#define OFF_WSQ1  1130496ul
#define OFF_ZERO  2179072ul
#define OFF_X0M   2179328ul       // bf16 NHWC [8][32][32][512]
#define OFF_W0T   10567936ul      // bf16 [9 slice][512 o][512 c]
#define OFF_W1T   15286528ul      // bf16 [9 tap][512 o][512 c]
#define OFF_ZZ    20005120ul      // bf16 [4 phase][8 b][33*33 q][512 o]
#define OFF_X1M   55689472ul      // bf16 NHWC [8][64][64][512] (s1-modulated)

// ---------- styles ----------
__global__ void styles_kernel(const float* __restrict__ wsv,
                              const float* __restrict__ a0w, const float* __restrict__ a0b,
                              const float* __restrict__ a1w, const float* __restrict__ a1b,
                              const float* __restrict__ argw, const float* __restrict__ argb,
                              float* __restrict__ s0, float* __restrict__ s1,
                              float* __restrict__ srgb) {
  const int idx = blockIdx.x * 4 + (threadIdx.x >> 6);
  const int lane = threadIdx.x & 63;
  const int l = idx >> 12, rem = idx & 4095, b = rem >> 9, o = rem & 511;
  const float* aw = (l == 0) ? a0w : ((l == 1) ? a1w : argw);
  const float* wrow = wsv + (b * 3 + l) * 512;
  const float* arow = aw + o * 512;
  float acc = 0.f;
#pragma unroll
  for (int k = 0; k < 8; ++k) acc += wrow[lane + 64 * k] * arow[lane + 64 * k];
#pragma unroll
  for (int off = 32; off; off >>= 1) acc += __shfl_xor(acc, off);
  if (lane == 0) {
    const float sg = 0.04419417382415922f;  // 1/sqrt(512)
    if (l == 0)      s0[b * 512 + o] = acc * sg + a0b[o];
    else if (l == 1) s1[b * 512 + o] = acc * sg + a1b[o];
    else             srgb[b * 512 + o] = (acc * sg + argb[o]) * sg;
  }
}

// ---------- w (512x512x3x3 f32) -> [slice][o][c] bf16 + wsq ----------
__global__ void prepWT_kernel(const float* __restrict__ w, u16* __restrict__ wt,
                              float* __restrict__ wsq) {
  const int idx = blockIdx.x * 256 + threadIdx.x;  // o*512+c
  float v[9], sq = 0.f;
#pragma unroll
  for (int t = 0; t < 9; ++t) { v[t] = w[idx * 9 + t]; sq += v[t] * v[t]; }
  wsq[idx] = sq;
#pragma unroll
  for (int t = 0; t < 9; ++t) wt[(size_t)t * 262144 + idx] = f2bf(v[t]);
}

// ---------- dcoef ----------
__global__ void dcoef_kernel(const float* __restrict__ s0, const float* __restrict__ s1,
                             const float* __restrict__ wsq0, const float* __restrict__ wsq1,
                             float* __restrict__ d0, float* __restrict__ d1) {
  const int idx = blockIdx.x * 4 + (threadIdx.x >> 6);
  const int lane = threadIdx.x & 63;
  const int layer = idx >> 12, rem = idx & 4095, b = rem >> 9, o = rem & 511;
  const float* s = layer ? s1 : s0;
  const float* wsq = layer ? wsq1 : wsq0;
  float acc = 0.f;
#pragma unroll
  for (int k = 0; k < 8; ++k) {
    const int c = lane + 64 * k;
    const float sv = s[b * 512 + c];
    acc += sv * sv * wsq[o * 512 + c];
  }
#pragma unroll
  for (int off = 32; off; off >>= 1) acc += __shfl_xor(acc, off);
  if (lane == 0) (layer ? d1 : d0)[b * 512 + o] = 1.f / sqrtf(acc + 1e-8f);
}

// ---------- x -> NHWC bf16 modulated by s0 ----------
__global__ void x0m_kernel(const float* __restrict__ x, const float* __restrict__ s0,
                           u16* __restrict__ out) {
  __shared__ u16 t[32 * 514];
  const int b = blockIdx.x >> 5, h = blockIdx.x & 31;
  const int tid = threadIdx.x;
  const int w = tid & 31, cs = tid >> 5;
  for (int c0 = 0; c0 < 512; c0 += 8) {
    const int c = c0 + cs;
    t[w * 514 + c] = f2bf(x[((b * 512 + c) * 32 + h) * 32 + w] * s0[b * 512 + c]);
  }
  __syncthreads();
  const int base = ((b * 32 + h) * 32) * 512;
  for (int i = 0; i < 64; ++i) {
    const int idx = i * 256 + tid;
    out[base + idx] = t[(idx >> 9) * 514 + (idx & 511)];
  }
}

// ---------- phase conv (transposed-conv phases of conv0, pre-FIR) ----------
// 8 waves / 512 threads per block; 128 couts x 256 px; one shared B-tile stage
// (halves B staging traffic vs 64-cout blocks). Per-wave MFMA code unchanged.
template <int PH>
DEV void phaseconv_body(char* smem, int tid, int lane, int wid,
                        int obp, int tile, int b,
                        const char* xin_c, const char* wt_c, u16* __restrict__ zz,
                        const char* __restrict__ zerobuf) {
  constexpr int NT = (PH == 0) ? 4 : ((PH == 3) ? 1 : 2);
  constexpr int SLt[4][4] = {{8, 6, 2, 0}, {7, 1, 0, 0}, {5, 3, 0, 0}, {4, 0, 0, 0}};
  constexpr int TYt[4][4] = {{0, 0, 1, 1}, {0, 1, 0, 0}, {1, 1, 0, 0}, {1, 0, 0, 0}};
  constexpr int TXt[4][4] = {{0, 1, 0, 1}, {1, 1, 0, 0}, {0, 1, 0, 0}, {1, 0, 0, 0}};
  constexpr int A_OFF = 24576;  // 3 B-chunks * 8192

  const int l15 = lane & 15, l4 = lane >> 4;
  const int cg = wid >> 2;      // cout group (0..1)
  const int pg = wid & 3;       // pixel group (0..3)
  const int obase = obp * 128 + cg * 64;

  const int p0 = tile * 256;
  const int r0 = (p0 * 993) >> 15;   // floor(p0/33), exact for p0<1280
  const int row0 = r0 - 1;

  // B staging: unit u = (row*4+k8)*34 + col, 1360 real units, 3 chunks x 512
  size_t boff[3];
  bool bval[3];
#pragma unroll
  for (int i = 0; i < 3; ++i) {
    const int u = i * 512 + tid;
    const int row = u / 136;
    const int rem = u - row * 136;
    const int k8 = rem / 34;
    const int col = rem - k8 * 34;
    const int ir = row0 + row;
    const int ic = col - 1;
    bval[i] = (u < 1360) && (ir >= 0) && (ir < 32) && (ic >= 0) && (ic < 32);
    boff[i] = ((size_t)((b * 32 + ir) * 32 + ic) * 512 + k8 * 8) * 2;
  }

  int ub[4], pp[4];
#pragma unroll
  for (int bc = 0; bc < 4; ++bc) {
    const int p = p0 + pg * 64 + bc * 16 + l15;
    pp[bc] = p;
    const int qy = (p * 993) >> 15;
    const int qx = p - qy * 33;
    ub[bc] = (((qy - r0) * 4 + l4) * 34 + qx) * 16;
  }

  // A staging: unit = k8*128 + cout_l; thread tid -> k8 = tid>>7, cout_l = tid&127
  const size_t aoffb = ((size_t)(obp * 128 + (tid & 127)) * 512 + (size_t)(tid >> 7) * 8) * 2;

  f32x4 acc[4][4];
  const f32x4 fz = {0.f, 0.f, 0.f, 0.f};
#pragma unroll
  for (int i = 0; i < 4; ++i)
#pragma unroll
    for (int j = 0; j < 4; ++j) acc[i][j] = fz;

  for (int c0 = 0; c0 < 512; c0 += 32) {
#pragma unroll
    for (int i = 0; i < 3; ++i) {
      const void* src = bval[i] ? (const void*)(xin_c + boff[i] + (size_t)c0 * 2)
                                : (const void*)zerobuf;
      gload16(src, smem + i * 8192 + wid * 1024);
    }
#pragma unroll
    for (int t = 0; t < NT; ++t)
      gload16(wt_c + (size_t)SLt[PH][t] * 524288 + aoffb + (size_t)c0 * 2,
              smem + A_OFF + t * 8192 + wid * 1024);
    __syncthreads();
#pragma unroll
    for (int t = 0; t < NT; ++t) {
      s16x8 bfr[4], afr[4];
#pragma unroll
      for (int bc = 0; bc < 4; ++bc)
        bfr[bc] = *(const s16x8*)(smem + ub[bc] + (TYt[PH][t] * 136 + TXt[PH][t]) * 16);
#pragma unroll
      for (int f = 0; f < 4; ++f)
        afr[f] = *(const s16x8*)(smem + A_OFF + t * 8192 +
                                 (l4 * 128 + cg * 64 + f * 16 + l15) * 16);
#pragma unroll
      for (int f = 0; f < 4; ++f)
#pragma unroll
        for (int bc = 0; bc < 4; ++bc)
          acc[f][bc] = mfma16(afr[f], bfr[bc], acc[f][bc]);
    }
    __syncthreads();
  }

  // epilogue: raw bf16 store of pre-FIR zz
#pragma unroll
  for (int f = 0; f < 4; ++f) {
    const int o = obase + f * 16 + l4 * 4;
#pragma unroll
    for (int bc = 0; bc < 4; ++bc) {
      if (pp[bc] < 1089) {
        ushort4 pk;
        pk.x = f2bf(acc[f][bc][0]);
        pk.y = f2bf(acc[f][bc][1]);
        pk.z = f2bf(acc[f][bc][2]);
        pk.w = f2bf(acc[f][bc][3]);
        *(ushort4*)(zz + ((size_t)(PH * 8 + b) * 1089 + pp[bc]) * 512 + o) = pk;
      }
    }
  }
}

__global__ __launch_bounds__(512, 2) void phaseconv_kernel(
    const u16* __restrict__ xin, const u16* __restrict__ wt, u16* __restrict__ zz,
    const char* __restrict__ zerobuf) {
  __shared__ __align__(16) char smem[57344];
  const int tid = threadIdx.x;
  const int lane = tid & 63, wid = tid >> 6;
  const int bid = blockIdx.x;       // ph-major so heavy blocks launch first
  const int ph = bid / 160;
  const int rem = bid - ph * 160;
  const int tile = rem >> 5;        // 0..4
  const int rem2 = rem & 31;
  const int b = rem2 >> 2;
  const int obp = rem2 & 3;
  const char* xin_c = (const char*)xin;
  const char* wt_c = (const char*)wt;
  switch (ph) {
    case 0: phaseconv_body<0>(smem, tid, lane, wid, obp, tile, b, xin_c, wt_c, zz, zerobuf); break;
    case 1: phaseconv_body<1>(smem, tid, lane, wid, obp, tile, b, xin_c, wt_c, zz, zerobuf); break;
    case 2: phaseconv_body<2>(smem, tid, lane, wid, obp, tile, b, xin_c, wt_c, zz, zerobuf); break;
    default: phaseconv_body<3>(smem, tid, lane, wid, obp, tile, b, xin_c, wt_c, zz, zerobuf); break;
  }
}

// ---------- FIR: LDS-tiled separable 4x4 upfirdn tail + demod+noise+bias+lrelu+s1 ----------
// block = (b, u-tile of 8 rows, 32-ch chunk). Stage zz patch once -> LDS (zero halo),
// horizontal FIR into 11 register rows, vertical FIR + epilogue, direct store.
// LDS patch: [ry(2)][qyi(6)][rx(2)][qxi(34)] cells x 80B (32 ch used, 80B stride).
__global__ __launch_bounds__(256) void fir_kernel(
    const u16* __restrict__ zz, const float* __restrict__ dc0,
    const float* __restrict__ bias0, const float* __restrict__ noise0,
    const float* __restrict__ ns0, const float* __restrict__ s1,
    u16* __restrict__ x1m) {
  __shared__ __align__(16) char smem[65280];   // 816 cells * 80B
  const int tid = threadIdx.x;
  const int cg = blockIdx.x & 15;          // ch chunk (32)
  const int t  = (blockIdx.x >> 4) & 7;    // u-tile
  const int b  = blockIdx.x >> 7;
  const int c0 = cg * 32;

  // ---- stage patch: 816 cells x 4 chunks of 16B = 3264 units ----
  const us8 zv0 = {0, 0, 0, 0, 0, 0, 0, 0};
  for (int it = 0; it < 13; ++it) {
    const int u = it * 256 + tid;
    if (u < 3264) {
      const int cell = u >> 2, j = u & 3;
      const int ry = cell / 408;
      const int r1 = cell - ry * 408;
      const int qyi = r1 / 68;
      const int r2 = r1 - qyi * 68;
      const int rx = r2 / 34;
      const int qxi = r2 - rx * 34;
      const int qy = 4 * t - 1 + qyi;
      const int qx = qxi - 1;
      us8 v = zv0;
      if (qy >= 0 && qy <= 32 && qx >= 0 && qx <= 32)
        v = *(const us8*)(zz + ((size_t)((ry * 2 + rx) * 8 + b) * 1089 + qy * 33 + qx) * 512 +
                          c0 + j * 8);
      *(us8*)(smem + cell * 80 + j * 16) = v;
    }
  }
  __syncthreads();

  // ---- compute: thread = (v, cs) ----
  const int v = tid & 63, cs = tid >> 6;
  const int cc = c0 + cs * 8;
  const float kk[4] = {0.25f, 0.75f, 0.75f, 0.25f};
  // horizontal tap params: parity e -> rx_e, qxi_e (kx=e), qxi_e+1 (kx=e+2)
  const int rx0 = (v - 1) & 1, qxi0 = ((v - 1) >> 1) + 1;
  const int rx1 = v & 1,       qxi1 = (v >> 1) + 1;
  const int ho0 = rx0 * 34 * 80 + qxi0 * 80 + cs * 16;
  const int ho1 = rx1 * 34 * 80 + qxi1 * 80 + cs * 16;

  float tmp[11][8];
#pragma unroll
  for (int i = 0; i < 11; ++i) {
    const int ry = (i + 1) & 1, qyi = (i + 1) >> 1;
    const char* pb = smem + ((ry * 6 + qyi) * 2) * 34 * 80;
    const us8 a0 = *(const us8*)(pb + ho0);
    const us8 a2 = *(const us8*)(pb + ho0 + 80);
    const us8 a1 = *(const us8*)(pb + ho1);
    const us8 a3 = *(const us8*)(pb + ho1 + 80);
#pragma unroll
    for (int r = 0; r < 8; ++r)
      tmp[i][r] = kk[0] * bf2f(a0[r]) + kk[2] * bf2f(a2[r]) +
                  kk[1] * bf2f(a1[r]) + kk[3] * bf2f(a3[r]);
  }

  // per-thread channel params
  float dcv[8], bv[8], sv[8];
#pragma unroll
  for (int r = 0; r < 8; ++r) {
    dcv[r] = dc0[b * 512 + cc + r];
    bv[r]  = bias0[cc + r];
    sv[r]  = s1[b * 512 + cc + r];
  }
  const float nsc = ns0[0];

#pragma unroll
  for (int ui = 0; ui < 8; ++ui) {
    const int u = 8 * t + ui;
    const float nz = noise0[u * 64 + v] * nsc;
    us8 pk;
#pragma unroll
    for (int r = 0; r < 8; ++r) {
      float a = kk[0] * tmp[ui][r] + kk[1] * tmp[ui + 1][r] +
                kk[2] * tmp[ui + 2][r] + kk[3] * tmp[ui + 3][r];
      float xv = a * dcv[r] + nz + bv[r];
      xv = (xv < 0.f ? 0.2f * xv : xv) * 1.4142135623730951f;
      xv = fminf(fmaxf(xv, -256.f), 256.f);
      pk[r] = f2bf(xv * sv[r]);
    }
    *(us8*)(x1m + ((size_t)((b * 64 + u) * 64 + v) * 512 + cc)) = pk;
  }
}

// ---------- conv1: implicit-GEMM MFMA 3x3 pad1 (round-1 verified structure) ----------
__global__ __launch_bounds__(256, 2) void conv1_kernel(
    const u16* __restrict__ xin, const u16* __restrict__ wt,
    const float* __restrict__ dcoef, const float* __restrict__ bias,
    const float* __restrict__ noise, const float* __restrict__ nstr,
    float* __restrict__ out_f32, const char* __restrict__ zerobuf) {
  __shared__ __align__(16) char smem[65536];
  const int tid = threadIdx.x;
  const int lane = tid & 63, wid = tid >> 6, l15 = lane & 15, l4 = lane >> 4;

  int bid = blockIdx.x;
  const int obIdx = bid & 7; bid >>= 3;
  const int tile = bid & 15;
  const int b = bid >> 4;
  const int obase = obIdx * 64;
  const int row0 = tile * 4 - 1;

  size_t boff[7];
  bool bval[7];
#pragma unroll
  for (int i = 0; i < 7; ++i) {
    const int u = i * 256 + tid;
    const int row = u / 264;
    const int rem = u - row * 264;
    const int k8 = rem / 66;
    const int col = rem - k8 * 66;
    const int ir = row0 + row;
    const int ic = col - 1;
    bval[i] = (row < 6) && (ir >= 0) && (ir < 64) && (ic >= 0) && (ic < 64);
    boff[i] = ((size_t)((b * 64 + ir) * 64 + ic) * 512 + k8 * 8) * 2;
  }

  int ub[4], jy[4], jx[4];
#pragma unroll
  for (int bc = 0; bc < 4; ++bc) {
    const int p = wid * 64 + bc * 16 + l15;
    const int pr = p >> 6, pc = p & 63;
    ub[bc] = ((pr * 4 + l4) * 66 + pc) * 16;
    jy[bc] = tile * 4 + pr;
    jx[bc] = pc;
  }

  const char* wt_c = (const char*)wt;
  const char* xin_c = (const char*)xin;
  const size_t aoffb = ((size_t)(obase + lane) * 512 + (size_t)wid * 8) * 2;

  f32x4 acc[4][4];
  const f32x4 fz = {0.f, 0.f, 0.f, 0.f};
#pragma unroll
  for (int i = 0; i < 4; ++i)
#pragma unroll
    for (int j = 0; j < 4; ++j) acc[i][j] = fz;

  for (int c0 = 0; c0 < 512; c0 += 32) {
#pragma unroll
    for (int i = 0; i < 7; ++i) {
      const void* src = bval[i] ? (const void*)(xin_c + boff[i] + (size_t)c0 * 2)
                                : (const void*)zerobuf;
      gload16(src, smem + i * 4096 + wid * 1024);
    }
#pragma unroll
    for (int t = 0; t < 9; ++t)
      gload16(wt_c + (size_t)t * 524288 + aoffb + (size_t)c0 * 2,
              smem + 28672 + t * 4096 + wid * 1024);
    __syncthreads();
#pragma unroll
    for (int t = 0; t < 9; ++t) {
      const int dyi = t / 3, dxi = t % 3;
      s16x8 bfr[4], afr[4];
#pragma unroll
      for (int bc = 0; bc < 4; ++bc)
        bfr[bc] = *(const s16x8*)(smem + ub[bc] + (dyi * 264 + dxi) * 16);
#pragma unroll
      for (int f = 0; f < 4; ++f)
        afr[f] = *(const s16x8*)(smem + 28672 + t * 4096 + (l4 * 64 + f * 16 + l15) * 16);
#pragma unroll
      for (int f = 0; f < 4; ++f)
#pragma unroll
        for (int bc = 0; bc < 4; ++bc)
          acc[f][bc] = mfma16(afr[f], bfr[bc], acc[f][bc]);
    }
    __syncthreads();
  }

  const float ns = nstr[0];
#pragma unroll
  for (int f = 0; f < 4; ++f) {
    const int o = obase + f * 16 + l4 * 4;
    const f32x4 dc = *(const f32x4*)(dcoef + b * 512 + o);
    const f32x4 bs = *(const f32x4*)(bias + o);
#pragma unroll
    for (int bc = 0; bc < 4; ++bc) {
      const float nz = noise[jy[bc] * 64 + jx[bc]] * ns;
#pragma unroll
      for (int r = 0; r < 4; ++r) {
        float xv = acc[f][bc][r] * dc[r] + nz + bs[r];
        xv = (xv < 0.f ? 0.2f * xv : xv) * 1.4142135623730951f;
        xv = fminf(fmaxf(xv, -256.f), 256.f);
        out_f32[((size_t)(b * 512 + o + r) * 64 + jy[bc]) * 64 + jx[bc]] = xv;
      }
    }
  }
}

// ---------- torgb (1x1 mod conv, f32) + img upsample + add ----------
__global__ void torgb_kernel(const float* __restrict__ xw, const float* __restrict__ img,
                             const float* __restrict__ srgb, const float* __restrict__ wrgb,
                             const float* __restrict__ brgb, float* __restrict__ imgout) {
  __shared__ float red[4][3][64];
  const int b = blockIdx.x >> 6, jy = blockIdx.x & 63;
  const int tid = threadIdx.x;
  const int jx = tid & 63, cg = tid >> 6;
  float p0 = 0.f, p1 = 0.f, p2 = 0.f;
  const float* xb = xw + ((size_t)(b * 512 + cg * 128) * 64 + jy) * 64 + jx;
  const float* sb = srgb + b * 512 + cg * 128;
  for (int i = 0; i < 128; ++i) {
    const float xs = xb[(size_t)i * 4096] * sb[i];
    const int c = cg * 128 + i;
    p0 += xs * wrgb[c];
    p1 += xs * wrgb[512 + c];
    p2 += xs * wrgb[1024 + c];
  }
  red[cg][0][jx] = p0; red[cg][1][jx] = p1; red[cg][2][jx] = p2;
  __syncthreads();
  if (cg == 0) {
    const int qy = jy >> 1, qx = jx >> 1;
    int ry[2]; float wy[2];
    if ((jy & 1) == 0) { ry[0] = qy - 1; wy[0] = 0.25f; ry[1] = qy; wy[1] = 0.75f; }
    else               { ry[0] = qy;     wy[0] = 0.75f; ry[1] = qy + 1; wy[1] = 0.25f; }
    int rx[2]; float wx[2];
    if ((jx & 1) == 0) { rx[0] = qx - 1; wx[0] = 0.25f; rx[1] = qx; wx[1] = 0.75f; }
    else               { rx[0] = qx;     wx[0] = 0.75f; rx[1] = qx + 1; wx[1] = 0.25f; }
#pragma unroll
    for (int o = 0; o < 3; ++o) {
      float y = red[0][o][jx] + red[1][o][jx] + red[2][o][jx] + red[3][o][jx] + brgb[o];
      y = fminf(fmaxf(y, -256.f), 256.f);
      float iv = 0.f;
#pragma unroll
      for (int a = 0; a < 2; ++a)
#pragma unroll
        for (int e = 0; e < 2; ++e)
          if (ry[a] >= 0 && ry[a] < 32 && rx[e] >= 0 && rx[e] < 32)
            iv += wy[a] * wx[e] * img[((b * 3 + o) * 32 + ry[a]) * 32 + rx[e]];
      imgout[((b * 3 + o) * 64 + jy) * 64 + jx] = y + iv;
    }
  }
}

// ---------- launch ----------
extern "C" void kernel_launch(void* const* d_in, const int* in_sizes, int n_in,
                              void* d_out, int out_size, void* d_ws, size_t ws_size,
                              hipStream_t stream) {
  (void)in_sizes; (void)n_in; (void)out_size; (void)ws_size;
  const float* x    = (const float*)d_in[0];
  const float* img  = (const float*)d_in[1];
  const float* wsv  = (const float*)d_in[2];
  const float* a0w  = (const float*)d_in[3];
  const float* a0b  = (const float*)d_in[4];
  const float* w0   = (const float*)d_in[5];
  const float* b0   = (const float*)d_in[6];
  const float* ns0  = (const float*)d_in[7];
  const float* nc0  = (const float*)d_in[8];
  const float* a1w  = (const float*)d_in[9];
  const float* a1b  = (const float*)d_in[10];
  const float* w1   = (const float*)d_in[11];
  const float* b1   = (const float*)d_in[12];
  const float* ns1  = (const float*)d_in[13];
  const float* nc1  = (const float*)d_in[14];
  const float* argw = (const float*)d_in[15];
  const float* argb = (const float*)d_in[16];
  const float* wrgb = (const float*)d_in[17];
  const float* brgb = (const float*)d_in[18];

  char* wsb = (char*)d_ws;
  float* s0   = (float*)(wsb + OFF_S0);
  float* s1   = (float*)(wsb + OFF_S1);
  float* srgb = (float*)(wsb + OFF_SRGB);
  float* dd0  = (float*)(wsb + OFF_D0);
  float* dd1  = (float*)(wsb + OFF_D1);
  float* wsq0 = (float*)(wsb + OFF_WSQ0);
  float* wsq1 = (float*)(wsb + OFF_WSQ1);
  char*  zero = wsb + OFF_ZERO;
  u16*   x0m  = (u16*)(wsb + OFF_X0M);
  u16*   w0t  = (u16*)(wsb + OFF_W0T);
  u16*   w1t  = (u16*)(wsb + OFF_W1T);
  u16*   zz   = (u16*)(wsb + OFF_ZZ);
  u16*   x1m  = (u16*)(wsb + OFF_X1M);

  float* out_x   = (float*)d_out;
  float* out_img = out_x + 16777216;

  hipMemsetAsync(zero, 0, 256, stream);
  styles_kernel<<<3072, 256, 0, stream>>>(wsv, a0w, a0b, a1w, a1b, argw, argb, s0, s1, srgb);
  prepWT_kernel<<<1024, 256, 0, stream>>>(w0, w0t, wsq0);
  prepWT_kernel<<<1024, 256, 0, stream>>>(w1, w1t, wsq1);
  dcoef_kernel<<<2048, 256, 0, stream>>>(s0, s1, wsq0, wsq1, dd0, dd1);
  x0m_kernel<<<256, 256, 0, stream>>>(x, s0, x0m);
  phaseconv_kernel<<<640, 512, 0, stream>>>(x0m, w0t, zz, zero);
  fir_kernel<<<1024, 256, 0, stream>>>(zz, dd0, b0, nc0, ns0, s1, x1m);
  conv1_kernel<<<1024, 256, 0, stream>>>(x1m, w1t, dd1, b1, nc1, ns1, out_x, zero);
  torgb_kernel<<<512, 256, 0, stream>>>(out_x, img, srgb, wrgb, brgb, out_img);
}

// Round 8
// 435.035 us; speedup vs baseline: 1.0881x; 1.0299x over previous
//
#include <hip/hip_runtime.h>
#include <hip/hip_bf16.h>
#include <stdint.h>

#define DEV __device__ __forceinline__

typedef float f32x4 __attribute__((ext_vector_type(4)));
typedef short s16x8 __attribute__((ext_vector_type(8)));
typedef __bf16 bf16x8 __attribute__((ext_vector_type(8)));
typedef unsigned short us8 __attribute__((ext_vector_type(8)));
typedef unsigned short u16;

// ---------- helpers ----------
DEV u16 f2bf(float f) {  // round-to-nearest-even f32 -> bf16
  uint32_t u = __builtin_bit_cast(uint32_t, f);
  u += 0x7FFFu + ((u >> 16) & 1u);
  return (u16)(u >> 16);
}
DEV float bf2f(u16 h) { return __builtin_bit_cast(float, (uint32_t)h << 16); }

DEV void gload16(const void* g, void* l) {
  __builtin_amdgcn_global_load_lds((__attribute__((address_space(1))) void*)(g),
                                   (__attribute__((address_space(3))) void*)(l),
                                   16, 0, 0);
}

DEV f32x4 mfma16(s16x8 a, s16x8 b, f32x4 c) {
  return __builtin_amdgcn_mfma_f32_16x16x32_bf16(
      __builtin_bit_cast(bf16x8, a), __builtin_bit_cast(bf16x8, b), c, 0, 0, 0);
}

// ---------- workspace layout (bytes) ----------
#define OFF_S0    0ul
#define OFF_S1    16384ul
#define OFF_SRGB  32768ul
#define OFF_D0    49152ul
#define OFF_D1    65536ul
#define OFF_WSQ0  81920ul
#define OFF_WSQ1  1130496ul
#define OFF_ZERO  2179072ul
#define OFF_X0M   2179328ul       // bf16 NHWC [8][32][32][512]
#define OFF_W0T   10567936ul      // bf16 [9 slice][512 o][512 c]
#define OFF_W1T   15286528ul      // bf16 [9 tap][512 o][512 c]
#define OFF_ZZ    20005120ul      // bf16 [4 phase][8 b][33*33 q][512 o]
#define OFF_X1M   55689472ul      // bf16 NHWC [8][64][64][512] (s1-modulated)

// ---------- fused prep: styles (3072) + prepWT w0 (1024) + prepWT w1 (1024) + zero (1) ----------
__global__ __launch_bounds__(256) void prep_kernel(
    const float* __restrict__ wsv,
    const float* __restrict__ a0w, const float* __restrict__ a0b,
    const float* __restrict__ a1w, const float* __restrict__ a1b,
    const float* __restrict__ argw, const float* __restrict__ argb,
    const float* __restrict__ w0, const float* __restrict__ w1,
    float* __restrict__ s0, float* __restrict__ s1, float* __restrict__ srgb,
    u16* __restrict__ w0t, float* __restrict__ wsq0,
    u16* __restrict__ w1t, float* __restrict__ wsq1,
    float* __restrict__ zero) {
  const int bid = blockIdx.x;
  const int tid = threadIdx.x;
  if (bid < 3072) {
    const int idx = bid * 4 + (tid >> 6);
    const int lane = tid & 63;
    const int l = idx >> 12, rem = idx & 4095, b = rem >> 9, o = rem & 511;
    const float* aw = (l == 0) ? a0w : ((l == 1) ? a1w : argw);
    const float* wrow = wsv + (b * 3 + l) * 512;
    const float* arow = aw + o * 512;
    float acc = 0.f;
#pragma unroll
    for (int k = 0; k < 8; ++k) acc += wrow[lane + 64 * k] * arow[lane + 64 * k];
#pragma unroll
    for (int off = 32; off; off >>= 1) acc += __shfl_xor(acc, off);
    if (lane == 0) {
      const float sg = 0.04419417382415922f;  // 1/sqrt(512)
      if (l == 0)      s0[b * 512 + o] = acc * sg + a0b[o];
      else if (l == 1) s1[b * 512 + o] = acc * sg + a1b[o];
      else             srgb[b * 512 + o] = (acc * sg + argb[o]) * sg;
    }
  } else if (bid < 5120) {
    const int which = (bid < 4096) ? 0 : 1;
    const float* w = which ? w1 : w0;
    u16* wt = which ? w1t : w0t;
    float* wsq = which ? wsq1 : wsq0;
    const int idx = ((bid - (which ? 4096 : 3072)) * 256 + tid);
    float v[9], sq = 0.f;
#pragma unroll
    for (int t = 0; t < 9; ++t) { v[t] = w[idx * 9 + t]; sq += v[t] * v[t]; }
    wsq[idx] = sq;
#pragma unroll
    for (int t = 0; t < 9; ++t) wt[(size_t)t * 262144 + idx] = f2bf(v[t]);
  } else {
    if (tid < 64) zero[tid] = 0.f;   // 256B zero buffer
  }
}

// ---------- fused dcoef (2048) + x0m (256) ----------
__global__ __launch_bounds__(256) void dcx_kernel(
    const float* __restrict__ s0, const float* __restrict__ s1,
    const float* __restrict__ wsq0, const float* __restrict__ wsq1,
    float* __restrict__ d0, float* __restrict__ d1,
    const float* __restrict__ x, u16* __restrict__ x0m) {
  __shared__ u16 t[32 * 514];
  const int tid = threadIdx.x;
  if (blockIdx.x < 2048) {
    const int idx = blockIdx.x * 4 + (tid >> 6);
    const int lane = tid & 63;
    const int layer = idx >> 12, rem = idx & 4095, b = rem >> 9, o = rem & 511;
    const float* s = layer ? s1 : s0;
    const float* wsq = layer ? wsq1 : wsq0;
    float acc = 0.f;
#pragma unroll
    for (int k = 0; k < 8; ++k) {
      const int c = lane + 64 * k;
      const float sv = s[b * 512 + c];
      acc += sv * sv * wsq[o * 512 + c];
    }
#pragma unroll
    for (int off = 32; off; off >>= 1) acc += __shfl_xor(acc, off);
    if (lane == 0) (layer ? d1 : d0)[b * 512 + o] = 1.f / sqrtf(acc + 1e-8f);
  } else {
    const int bid = blockIdx.x - 2048;
    const int b = bid >> 5, h = bid & 31;
    const int w = tid & 31, cs = tid >> 5;
    for (int c0 = 0; c0 < 512; c0 += 8) {
      const int c = c0 + cs;
      t[w * 514 + c] = f2bf(x[((b * 512 + c) * 32 + h) * 32 + w] * s0[b * 512 + c]);
    }
    __syncthreads();
    const int base = ((b * 32 + h) * 32) * 512;
    for (int i = 0; i < 64; ++i) {
      const int idx = i * 256 + tid;
      x0m[base + idx] = t[(idx >> 9) * 514 + (idx & 511)];
    }
  }
}

// ---------- phase conv (transposed-conv phases of conv0, pre-FIR) ----------
template <int PH>
DEV void phaseconv_body(char* smem, int tid, int lane, int wid,
                        int obp, int tile, int b,
                        const char* xin_c, const char* wt_c, u16* __restrict__ zz,
                        const char* __restrict__ zerobuf) {
  constexpr int NT = (PH == 0) ? 4 : ((PH == 3) ? 1 : 2);
  constexpr int SLt[4][4] = {{8, 6, 2, 0}, {7, 1, 0, 0}, {5, 3, 0, 0}, {4, 0, 0, 0}};
  constexpr int TYt[4][4] = {{0, 0, 1, 1}, {0, 1, 0, 0}, {1, 1, 0, 0}, {1, 0, 0, 0}};
  constexpr int TXt[4][4] = {{0, 1, 0, 1}, {1, 1, 0, 0}, {0, 1, 0, 0}, {1, 0, 0, 0}};
  constexpr int A_OFF = 24576;  // 3 B-chunks * 8192

  const int l15 = lane & 15, l4 = lane >> 4;
  const int cg = wid >> 2;      // cout group (0..1)
  const int pg = wid & 3;       // pixel group (0..3)
  const int obase = obp * 128 + cg * 64;

  const int p0 = tile * 256;
  const int r0 = (p0 * 993) >> 15;   // floor(p0/33), exact for p0<1280
  const int row0 = r0 - 1;

  size_t boff[3];
  bool bval[3];
#pragma unroll
  for (int i = 0; i < 3; ++i) {
    const int u = i * 512 + tid;
    const int row = u / 136;
    const int rem = u - row * 136;
    const int k8 = rem / 34;
    const int col = rem - k8 * 34;
    const int ir = row0 + row;
    const int ic = col - 1;
    bval[i] = (u < 1360) && (ir >= 0) && (ir < 32) && (ic >= 0) && (ic < 32);
    boff[i] = ((size_t)((b * 32 + ir) * 32 + ic) * 512 + k8 * 8) * 2;
  }

  int ub[4], pp[4];
#pragma unroll
  for (int bc = 0; bc < 4; ++bc) {
    const int p = p0 + pg * 64 + bc * 16 + l15;
    pp[bc] = p;
    const int qy = (p * 993) >> 15;
    const int qx = p - qy * 33;
    ub[bc] = (((qy - r0) * 4 + l4) * 34 + qx) * 16;
  }

  const size_t aoffb = ((size_t)(obp * 128 + (tid & 127)) * 512 + (size_t)(tid >> 7) * 8) * 2;

  f32x4 acc[4][4];
  const f32x4 fz = {0.f, 0.f, 0.f, 0.f};
#pragma unroll
  for (int i = 0; i < 4; ++i)
#pragma unroll
    for (int j = 0; j < 4; ++j) acc[i][j] = fz;

  for (int c0 = 0; c0 < 512; c0 += 32) {
#pragma unroll
    for (int i = 0; i < 3; ++i) {
      const void* src = bval[i] ? (const void*)(xin_c + boff[i] + (size_t)c0 * 2)
                                : (const void*)zerobuf;
      gload16(src, smem + i * 8192 + wid * 1024);
    }
#pragma unroll
    for (int t = 0; t < NT; ++t)
      gload16(wt_c + (size_t)SLt[PH][t] * 524288 + aoffb + (size_t)c0 * 2,
              smem + A_OFF + t * 8192 + wid * 1024);
    __syncthreads();
#pragma unroll
    for (int t = 0; t < NT; ++t) {
      s16x8 bfr[4], afr[4];
#pragma unroll
      for (int bc = 0; bc < 4; ++bc)
        bfr[bc] = *(const s16x8*)(smem + ub[bc] + (TYt[PH][t] * 136 + TXt[PH][t]) * 16);
#pragma unroll
      for (int f = 0; f < 4; ++f)
        afr[f] = *(const s16x8*)(smem + A_OFF + t * 8192 +
                                 (l4 * 128 + cg * 64 + f * 16 + l15) * 16);
#pragma unroll
      for (int f = 0; f < 4; ++f)
#pragma unroll
        for (int bc = 0; bc < 4; ++bc)
          acc[f][bc] = mfma16(afr[f], bfr[bc], acc[f][bc]);
    }
    __syncthreads();
  }

#pragma unroll
  for (int f = 0; f < 4; ++f) {
    const int o = obase + f * 16 + l4 * 4;
#pragma unroll
    for (int bc = 0; bc < 4; ++bc) {
      if (pp[bc] < 1089) {
        ushort4 pk;
        pk.x = f2bf(acc[f][bc][0]);
        pk.y = f2bf(acc[f][bc][1]);
        pk.z = f2bf(acc[f][bc][2]);
        pk.w = f2bf(acc[f][bc][3]);
        *(ushort4*)(zz + ((size_t)(PH * 8 + b) * 1089 + pp[bc]) * 512 + o) = pk;
      }
    }
  }
}

__global__ __launch_bounds__(512, 2) void phaseconv_kernel(
    const u16* __restrict__ xin, const u16* __restrict__ wt, u16* __restrict__ zz,
    const char* __restrict__ zerobuf) {
  __shared__ __align__(16) char smem[57344];
  const int tid = threadIdx.x;
  const int lane = tid & 63, wid = tid >> 6;
  const int bid = blockIdx.x;       // ph-major so heavy blocks launch first
  const int ph = bid / 160;
  const int rem = bid - ph * 160;
  const int tile = rem >> 5;        // 0..4
  const int rem2 = rem & 31;
  const int b = rem2 >> 2;
  const int obp = rem2 & 3;
  const char* xin_c = (const char*)xin;
  const char* wt_c = (const char*)wt;
  switch (ph) {
    case 0: phaseconv_body<0>(smem, tid, lane, wid, obp, tile, b, xin_c, wt_c, zz, zerobuf); break;
    case 1: phaseconv_body<1>(smem, tid, lane, wid, obp, tile, b, xin_c, wt_c, zz, zerobuf); break;
    case 2: phaseconv_body<2>(smem, tid, lane, wid, obp, tile, b, xin_c, wt_c, zz, zerobuf); break;
    default: phaseconv_body<3>(smem, tid, lane, wid, obp, tile, b, xin_c, wt_c, zz, zerobuf); break;
  }
}

// ---------- FIR: LDS-tiled separable 4x4 upfirdn tail + demod+noise+bias+lrelu+s1 ----------
__global__ __launch_bounds__(256) void fir_kernel(
    const u16* __restrict__ zz, const float* __restrict__ dc0,
    const float* __restrict__ bias0, const float* __restrict__ noise0,
    const float* __restrict__ ns0, const float* __restrict__ s1,
    u16* __restrict__ x1m) {
  __shared__ __align__(16) char smem[65280];   // 816 cells * 80B
  const int tid = threadIdx.x;
  const int cg = blockIdx.x & 15;          // ch chunk (32)
  const int t  = (blockIdx.x >> 4) & 7;    // u-tile
  const int b  = blockIdx.x >> 7;
  const int c0 = cg * 32;

  const us8 zv0 = {0, 0, 0, 0, 0, 0, 0, 0};
  for (int it = 0; it < 13; ++it) {
    const int u = it * 256 + tid;
    if (u < 3264) {
      const int cell = u >> 2, j = u & 3;
      const int ry = cell / 408;
      const int r1 = cell - ry * 408;
      const int qyi = r1 / 68;
      const int r2 = r1 - qyi * 68;
      const int rx = r2 / 34;
      const int qxi = r2 - rx * 34;
      const int qy = 4 * t - 1 + qyi;
      const int qx = qxi - 1;
      us8 v = zv0;
      if (qy >= 0 && qy <= 32 && qx >= 0 && qx <= 32)
        v = *(const us8*)(zz + ((size_t)((ry * 2 + rx) * 8 + b) * 1089 + qy * 33 + qx) * 512 +
                          c0 + j * 8);
      *(us8*)(smem + cell * 80 + j * 16) = v;
    }
  }
  __syncthreads();

  const int v = tid & 63, cs = tid >> 6;
  const int cc = c0 + cs * 8;
  const float kk[4] = {0.25f, 0.75f, 0.75f, 0.25f};
  const int rx0 = (v - 1) & 1, qxi0 = ((v - 1) >> 1) + 1;
  const int rx1 = v & 1,       qxi1 = (v >> 1) + 1;
  const int ho0 = rx0 * 34 * 80 + qxi0 * 80 + cs * 16;
  const int ho1 = rx1 * 34 * 80 + qxi1 * 80 + cs * 16;

  float tmp[11][8];
#pragma unroll
  for (int i = 0; i < 11; ++i) {
    const int ry = (i + 1) & 1, qyi = (i + 1) >> 1;
    const char* pb = smem + ((ry * 6 + qyi) * 2) * 34 * 80;
    const us8 a0 = *(const us8*)(pb + ho0);
    const us8 a2 = *(const us8*)(pb + ho0 + 80);
    const us8 a1 = *(const us8*)(pb + ho1);
    const us8 a3 = *(const us8*)(pb + ho1 + 80);
#pragma unroll
    for (int r = 0; r < 8; ++r)
      tmp[i][r] = kk[0] * bf2f(a0[r]) + kk[2] * bf2f(a2[r]) +
                  kk[1] * bf2f(a1[r]) + kk[3] * bf2f(a3[r]);
  }

  float dcv[8], bv[8], sv[8];
#pragma unroll
  for (int r = 0; r < 8; ++r) {
    dcv[r] = dc0[b * 512 + cc + r];
    bv[r]  = bias0[cc + r];
    sv[r]  = s1[b * 512 + cc + r];
  }
  const float nsc = ns0[0];

#pragma unroll
  for (int ui = 0; ui < 8; ++ui) {
    const int u = 8 * t + ui;
    const float nz = noise0[u * 64 + v] * nsc;
    us8 pk;
#pragma unroll
    for (int r = 0; r < 8; ++r) {
      float a = kk[0] * tmp[ui][r] + kk[1] * tmp[ui + 1][r] +
                kk[2] * tmp[ui + 2][r] + kk[3] * tmp[ui + 3][r];
      float xv = a * dcv[r] + nz + bv[r];
      xv = (xv < 0.f ? 0.2f * xv : xv) * 1.4142135623730951f;
      xv = fminf(fmaxf(xv, -256.f), 256.f);
      pk[r] = f2bf(xv * sv[r]);
    }
    *(us8*)(x1m + ((size_t)((b * 64 + u) * 64 + v) * 512 + cc)) = pk;
  }
}

// ---------- conv1: implicit-GEMM MFMA 3x3 pad1 (split into 2 dispatches) ----------
__global__ __launch_bounds__(256, 2) void conv1_kernel(
    const u16* __restrict__ xin, const u16* __restrict__ wt,
    const float* __restrict__ dcoef, const float* __restrict__ bias,
    const float* __restrict__ noise, const float* __restrict__ nstr,
    float* __restrict__ out_f32, const char* __restrict__ zerobuf, int bofs) {
  __shared__ __align__(16) char smem[65536];
  const int tid = threadIdx.x;
  const int lane = tid & 63, wid = tid >> 6, l15 = lane & 15, l4 = lane >> 4;

  int bid = blockIdx.x + bofs;
  const int obIdx = bid & 7; bid >>= 3;
  const int tile = bid & 15;
  const int b = bid >> 4;
  const int obase = obIdx * 64;
  const int row0 = tile * 4 - 1;

  size_t boff[7];
  bool bval[7];
#pragma unroll
  for (int i = 0; i < 7; ++i) {
    const int u = i * 256 + tid;
    const int row = u / 264;
    const int rem = u - row * 264;
    const int k8 = rem / 66;
    const int col = rem - k8 * 66;
    const int ir = row0 + row;
    const int ic = col - 1;
    bval[i] = (row < 6) && (ir >= 0) && (ir < 64) && (ic >= 0) && (ic < 64);
    boff[i] = ((size_t)((b * 64 + ir) * 64 + ic) * 512 + k8 * 8) * 2;
  }

  int ub[4], jy[4], jx[4];
#pragma unroll
  for (int bc = 0; bc < 4; ++bc) {
    const int p = wid * 64 + bc * 16 + l15;
    const int pr = p >> 6, pc = p & 63;
    ub[bc] = ((pr * 4 + l4) * 66 + pc) * 16;
    jy[bc] = tile * 4 + pr;
    jx[bc] = pc;
  }

  const char* wt_c = (const char*)wt;
  const char* xin_c = (const char*)xin;
  const size_t aoffb = ((size_t)(obase + lane) * 512 + (size_t)wid * 8) * 2;

  f32x4 acc[4][4];
  const f32x4 fz = {0.f, 0.f, 0.f, 0.f};
#pragma unroll
  for (int i = 0; i < 4; ++i)
#pragma unroll
    for (int j = 0; j < 4; ++j) acc[i][j] = fz;

  for (int c0 = 0; c0 < 512; c0 += 32) {
#pragma unroll
    for (int i = 0; i < 7; ++i) {
      const void* src = bval[i] ? (const void*)(xin_c + boff[i] + (size_t)c0 * 2)
                                : (const void*)zerobuf;
      gload16(src, smem + i * 4096 + wid * 1024);
    }
#pragma unroll
    for (int t = 0; t < 9; ++t)
      gload16(wt_c + (size_t)t * 524288 + aoffb + (size_t)c0 * 2,
              smem + 28672 + t * 4096 + wid * 1024);
    __syncthreads();
#pragma unroll
    for (int t = 0; t < 9; ++t) {
      const int dyi = t / 3, dxi = t % 3;
      s16x8 bfr[4], afr[4];
#pragma unroll
      for (int bc = 0; bc < 4; ++bc)
        bfr[bc] = *(const s16x8*)(smem + ub[bc] + (dyi * 264 + dxi) * 16);
#pragma unroll
      for (int f = 0; f < 4; ++f)
        afr[f] = *(const s16x8*)(smem + 28672 + t * 4096 + (l4 * 64 + f * 16 + l15) * 16);
#pragma unroll
      for (int f = 0; f < 4; ++f)
#pragma unroll
        for (int bc = 0; bc < 4; ++bc)
          acc[f][bc] = mfma16(afr[f], bfr[bc], acc[f][bc]);
    }
    __syncthreads();
  }

  const float ns = nstr[0];
#pragma unroll
  for (int f = 0; f < 4; ++f) {
    const int o = obase + f * 16 + l4 * 4;
    const f32x4 dc = *(const f32x4*)(dcoef + b * 512 + o);
    const f32x4 bs = *(const f32x4*)(bias + o);
#pragma unroll
    for (int bc = 0; bc < 4; ++bc) {
      const float nz = noise[jy[bc] * 64 + jx[bc]] * ns;
#pragma unroll
      for (int r = 0; r < 4; ++r) {
        float xv = acc[f][bc][r] * dc[r] + nz + bs[r];
        xv = (xv < 0.f ? 0.2f * xv : xv) * 1.4142135623730951f;
        xv = fminf(fmaxf(xv, -256.f), 256.f);
        out_f32[((size_t)(b * 512 + o + r) * 64 + jy[bc]) * 64 + jx[bc]] = xv;
      }
    }
  }
}

// ---------- torgb (1x1 mod conv, f32) + img upsample + add ----------
__global__ void torgb_kernel(const float* __restrict__ xw, const float* __restrict__ img,
                             const float* __restrict__ srgb, const float* __restrict__ wrgb,
                             const float* __restrict__ brgb, float* __restrict__ imgout) {
  __shared__ float red[4][3][64];
  const int b = blockIdx.x >> 6, jy = blockIdx.x & 63;
  const int tid = threadIdx.x;
  const int jx = tid & 63, cg = tid >> 6;
  float p0 = 0.f, p1 = 0.f, p2 = 0.f;
  const float* xb = xw + ((size_t)(b * 512 + cg * 128) * 64 + jy) * 64 + jx;
  const float* sb = srgb + b * 512 + cg * 128;
  for (int i = 0; i < 128; ++i) {
    const float xs = xb[(size_t)i * 4096] * sb[i];
    const int c = cg * 128 + i;
    p0 += xs * wrgb[c];
    p1 += xs * wrgb[512 + c];
    p2 += xs * wrgb[1024 + c];
  }
  red[cg][0][jx] = p0; red[cg][1][jx] = p1; red[cg][2][jx] = p2;
  __syncthreads();
  if (cg == 0) {
    const int qy = jy >> 1, qx = jx >> 1;
    int ry[2]; float wy[2];
    if ((jy & 1) == 0) { ry[0] = qy - 1; wy[0] = 0.25f; ry[1] = qy; wy[1] = 0.75f; }
    else               { ry[0] = qy;     wy[0] = 0.75f; ry[1] = qy + 1; wy[1] = 0.25f; }
    int rx[2]; float wx[2];
    if ((jx & 1) == 0) { rx[0] = qx - 1; wx[0] = 0.25f; rx[1] = qx; wx[1] = 0.75f; }
    else               { rx[0] = qx;     wx[0] = 0.75f; rx[1] = qx + 1; wx[1] = 0.25f; }
#pragma unroll
    for (int o = 0; o < 3; ++o) {
      float y = red[0][o][jx] + red[1][o][jx] + red[2][o][jx] + red[3][o][jx] + brgb[o];
      y = fminf(fmaxf(y, -256.f), 256.f);
      float iv = 0.f;
#pragma unroll
      for (int a = 0; a < 2; ++a)
#pragma unroll
        for (int e = 0; e < 2; ++e)
          if (ry[a] >= 0 && ry[a] < 32 && rx[e] >= 0 && rx[e] < 32)
            iv += wy[a] * wx[e] * img[((b * 3 + o) * 32 + ry[a]) * 32 + rx[e]];
      imgout[((b * 3 + o) * 64 + jy) * 64 + jx] = y + iv;
    }
  }
}

// ---------- launch ----------
extern "C" void kernel_launch(void* const* d_in, const int* in_sizes, int n_in,
                              void* d_out, int out_size, void* d_ws, size_t ws_size,
                              hipStream_t stream) {
  (void)in_sizes; (void)n_in; (void)out_size; (void)ws_size;
  const float* x    = (const float*)d_in[0];
  const float* img  = (const float*)d_in[1];
  const float* wsv  = (const float*)d_in[2];
  const float* a0w  = (const float*)d_in[3];
  const float* a0b  = (const float*)d_in[4];
  const float* w0   = (const float*)d_in[5];
  const float* b0   = (const float*)d_in[6];
  const float* ns0  = (const float*)d_in[7];
  const float* nc0  = (const float*)d_in[8];
  const float* a1w  = (const float*)d_in[9];
  const float* a1b  = (const float*)d_in[10];
  const float* w1   = (const float*)d_in[11];
  const float* b1   = (const float*)d_in[12];
  const float* ns1  = (const float*)d_in[13];
  const float* nc1  = (const float*)d_in[14];
  const float* argw = (const float*)d_in[15];
  const float* argb = (const float*)d_in[16];
  const float* wrgb = (const float*)d_in[17];
  const float* brgb = (const float*)d_in[18];

  char* wsb = (char*)d_ws;
  float* s0   = (float*)(wsb + OFF_S0);
  float* s1   = (float*)(wsb + OFF_S1);
  float* srgb = (float*)(wsb + OFF_SRGB);
  float* dd0  = (float*)(wsb + OFF_D0);
  float* dd1  = (float*)(wsb + OFF_D1);
  float* wsq0 = (float*)(wsb + OFF_WSQ0);
  float* wsq1 = (float*)(wsb + OFF_WSQ1);
  char*  zero = wsb + OFF_ZERO;
  u16*   x0m  = (u16*)(wsb + OFF_X0M);
  u16*   w0t  = (u16*)(wsb + OFF_W0T);
  u16*   w1t  = (u16*)(wsb + OFF_W1T);
  u16*   zz   = (u16*)(wsb + OFF_ZZ);
  u16*   x1m  = (u16*)(wsb + OFF_X1M);

  float* out_x   = (float*)d_out;
  float* out_img = out_x + 16777216;

  prep_kernel<<<5121, 256, 0, stream>>>(wsv, a0w, a0b, a1w, a1b, argw, argb, w0, w1,
                                        s0, s1, srgb, w0t, wsq0, w1t, wsq1, (float*)zero);
  dcx_kernel<<<2304, 256, 0, stream>>>(s0, s1, wsq0, wsq1, dd0, dd1, x, x0m);
  phaseconv_kernel<<<640, 512, 0, stream>>>(x0m, w0t, zz, zero);
  fir_kernel<<<1024, 256, 0, stream>>>(zz, dd0, b0, nc0, ns0, s1, x1m);
  conv1_kernel<<<512, 256, 0, stream>>>(x1m, w1t, dd1, b1, nc1, ns1, out_x, zero, 0);
  conv1_kernel<<<512, 256, 0, stream>>>(x1m, w1t, dd1, b1, nc1, ns1, out_x, zero, 512);
  torgb_kernel<<<512, 256, 0, stream>>>(out_x, img, srgb, wrgb, brgb, out_img);
}